// Round 17
// baseline (4582.946 us; speedup 1.0000x reference)
//
#include <hip/hip_runtime.h>
#include <hip/hip_cooperative_groups.h>
#include <math.h>

namespace cg = cooperative_groups;

#define NBATCH 4
#define NTOK 197
#define TT 788
#define DM 384
#define HM 1536
#define NHEAD 6
#define NEXP 8
#define LD2 72

typedef __attribute__((ext_vector_type(8))) short bf16x8;
typedef __attribute__((ext_vector_type(4))) float f32x4;

__device__ __forceinline__ void f2bf2(float x, short& hi, short& lo) {
    unsigned u = __float_as_uint(x);
    unsigned uh = u + (0x7fffu + ((u >> 16) & 1u));
    hi = (short)(uh >> 16);
    float hf = __uint_as_float(uh & 0xffff0000u);
    float r = x - hf;
    unsigned v = __float_as_uint(r);
    lo = (short)((v + (0x7fffu + ((v >> 16) & 1u))) >> 16);
}
__device__ __forceinline__ float gelu_f(float x) {
    return 0.5f * x * (1.0f + erff(x * 0.7071067811865475f));
}

struct MParams {
    const float *x, *patch_w, *patch_b, *cls_token, *pos_embed;
    const float *ln1_w, *ln1_b, *qkv_w, *qkv_b, *proj_w, *proj_b;
    const float *ln2_w, *ln2_b, *fc1_w, *fc1_b, *fc2_w, *fc2_b;
    const float *gate_w, *moe_w1, *moe_b1, *moe_w2, *moe_b2;
    const float *lnf_w, *lnf_b;
    float *out;
    float *h, *qkvb, *attno, *S, *hid, *moehid;
    float *egate, *lnstat, *slot_gate;
    int *eidx, *slot_tok, *cnt, *basep;
};

// ---------------- GEMM phase body (virtual block vb) ----------------
__device__ void gemm_dev(int vb, float* smem,
                         const float* A, const float* W, const float* bias, float* C,
                         int M, int N, int K, int flags, int MT, int NT, int wprot, int ksplit,
                         const float* lnw, const float* lnb)
{
    int mt, nt, ks = 0;
    {
        int lane8 = vb & 7;
        int idx = vb >> 3;
        if (ksplit > 1) { ks = idx % ksplit; idx /= ksplit; }
        if (wprot) {
            mt = idx % MT;
            nt = lane8 + 8 * (idx / MT);
            if (nt >= NT) return;
        } else {
            nt = idx % NT;
            mt = lane8 + 8 * (idx / NT);
            if (mt >= MT) return;
        }
    }
    const int Ks = K / ksplit;
    const float* Ab = A + (size_t)ks * Ks;
    const float* Wb = W + (size_t)ks * Ks;
    short* Ah = (short*)smem;
    short* Al = Ah + 64 * LD2;
    short* Bh = Al + 64 * LD2;
    short* Bl = Bh + 64 * LD2;
    const int bm = mt * 64, bn = nt * 64;
    const int tid = threadIdx.x;
    const int lane = tid & 63, w = tid >> 6;
    const int wr = w >> 1, wc = w & 1;
    const int r16 = lane & 15, g = lane >> 4;
    const int sr = tid >> 4;
    const int sc = (tid & 15) * 4;
    const bool doln = (flags & 8) != 0;
    const bool dogelu_a = (flags & 32) != 0;
    float am[4], ai[4];
    #pragma unroll
    for (int p = 0; p < 4; ++p) { am[p] = 0.f; ai[p] = 1.f; }
    if (doln) {
        int j = tid & 15;
        #pragma unroll
        for (int p = 0; p < 4; ++p) {
            int r = bm + sr + p * 16;
            if (r < M) {
                const float* xr = A + (size_t)r * K;
                float s = 0.f, ss = 0.f;
                #pragma unroll
                for (int i = 0; i < 6; ++i) {
                    float4 v = *(const float4*)(xr + j * 4 + i * 64);
                    s += v.x + v.y + v.z + v.w;
                    ss += v.x * v.x + v.y * v.y + v.z * v.z + v.w * v.w;
                }
                #pragma unroll
                for (int off = 1; off < 16; off <<= 1) {
                    s += __shfl_xor(s, off);
                    ss += __shfl_xor(ss, off);
                }
                float mean = s * (1.f / 384.f);
                float var = ss * (1.f / 384.f) - mean * mean;
                am[p] = mean;
                ai[p] = rsqrtf(var + 1e-6f);
            }
        }
    }
    float4 ra[4], rb[4], lw4, lb4;
    auto LOADT = [&](int k0) {
        if (doln) {
            lw4 = *(const float4*)(lnw + k0 + sc);
            lb4 = *(const float4*)(lnb + k0 + sc);
        }
        #pragma unroll
        for (int p = 0; p < 4; ++p) {
            int r = sr + p * 16;
            ra[p] = make_float4(0.f, 0.f, 0.f, 0.f);
            if (bm + r < M) ra[p] = *(const float4*)(Ab + (size_t)(bm + r) * K + k0 + sc);
            rb[p] = *(const float4*)(Wb + (size_t)(bn + r) * K + k0 + sc);
        }
    };
    auto STORET = [&]() {
        #pragma unroll
        for (int p = 0; p < 4; ++p) {
            int r = sr + p * 16;
            float4 a4 = ra[p];
            if (dogelu_a) {
                a4.x = gelu_f(a4.x); a4.y = gelu_f(a4.y);
                a4.z = gelu_f(a4.z); a4.w = gelu_f(a4.w);
            }
            if (doln) {
                a4.x = (a4.x - am[p]) * ai[p] * lw4.x + lb4.x;
                a4.y = (a4.y - am[p]) * ai[p] * lw4.y + lb4.y;
                a4.z = (a4.z - am[p]) * ai[p] * lw4.z + lb4.z;
                a4.w = (a4.w - am[p]) * ai[p] * lw4.w + lb4.w;
            }
            float4 b4 = rb[p];
            short4 ah, al, bh, bl;
            f2bf2(a4.x, ah.x, al.x); f2bf2(a4.y, ah.y, al.y);
            f2bf2(a4.z, ah.z, al.z); f2bf2(a4.w, ah.w, al.w);
            f2bf2(b4.x, bh.x, bl.x); f2bf2(b4.y, bh.y, bl.y);
            f2bf2(b4.z, bh.z, bl.z); f2bf2(b4.w, bh.w, bl.w);
            *(short4*)&Ah[r * LD2 + sc] = ah; *(short4*)&Al[r * LD2 + sc] = al;
            *(short4*)&Bh[r * LD2 + sc] = bh; *(short4*)&Bl[r * LD2 + sc] = bl;
        }
    };
    f32x4 acc[2][2] = {};
    auto COMPUTE = [&]() {
        #pragma unroll
        for (int kk = 0; kk < 2; ++kk) {
            bf16x8 afh[2], afl[2], bfh[2], bfl[2];
            #pragma unroll
            for (int i = 0; i < 2; ++i) {
                int off = (wr * 32 + i * 16 + r16) * LD2 + kk * 32 + g * 8;
                afh[i] = *(const bf16x8*)&Ah[off];
                afl[i] = *(const bf16x8*)&Al[off];
            }
            #pragma unroll
            for (int j = 0; j < 2; ++j) {
                int off = (wc * 32 + j * 16 + r16) * LD2 + kk * 32 + g * 8;
                bfh[j] = *(const bf16x8*)&Bh[off];
                bfl[j] = *(const bf16x8*)&Bl[off];
            }
            #pragma unroll
            for (int i = 0; i < 2; ++i)
                #pragma unroll
                for (int j = 0; j < 2; ++j) {
                    acc[i][j] = __builtin_amdgcn_mfma_f32_16x16x32_bf16(afl[i], bfh[j], acc[i][j], 0, 0, 0);
                    acc[i][j] = __builtin_amdgcn_mfma_f32_16x16x32_bf16(afh[i], bfl[j], acc[i][j], 0, 0, 0);
                    acc[i][j] = __builtin_amdgcn_mfma_f32_16x16x32_bf16(afh[i], bfh[j], acc[i][j], 0, 0, 0);
                }
        }
    };
    LOADT(0);
    STORET();
    __syncthreads();
    for (int k0 = 64; k0 < Ks; k0 += 64) {
        LOADT(k0);
        COMPUTE();
        __syncthreads();
        STORET();
        __syncthreads();
    }
    COMPUTE();
    #pragma unroll
    for (int i = 0; i < 2; ++i) {
        #pragma unroll
        for (int j = 0; j < 2; ++j) {
            int n = bn + wc * 32 + j * 16 + r16;
            float bb = (bias && ks == 0) ? bias[n] : 0.f;
            int mbase = bm + wr * 32 + i * 16 + g * 4;
            #pragma unroll
            for (int r = 0; r < 4; ++r) {
                int m = mbase + r;
                if (m < M) {
                    float v = acc[i][j][r] + bb;
                    float* cp = C + (size_t)m * N + n;
                    if (flags & 16) atomicAdd(cp, v);
                    else *cp = v;
                }
            }
        }
    }
}

// ---------------- patch embed phase body ----------------
__device__ void patch_dev(int vb, float* smem,
                          const float* X, const float* W, const float* pb,
                          const float* cls, const float* pos, float* H)
{
    const int M = 784, K = 768, NT = 6;
    int mt, nt;
    {
        int lane8 = vb & 7;
        int idx = vb >> 3;
        nt = idx % NT;
        mt = lane8 + 8 * (idx / NT);
    }
    const int tid = threadIdx.x;
    if (vb == 0) {
        // cls rows handled below after main tile (uniform path first)
    }
    if (mt >= 13) {
        if (vb == 0) {
            for (int idx2 = tid; idx2 < NBATCH * DM; idx2 += 256) {
                int b = idx2 / DM, d = idx2 % DM;
                H[(size_t)(b * NTOK) * DM + d] = cls[d] + pos[d];
            }
        }
        return;
    }
    short* Ah = (short*)smem;
    short* Al = Ah + 64 * LD2;
    short* Bh = Al + 64 * LD2;
    short* Bl = Bh + 64 * LD2;
    const int bm = mt * 64, bn = nt * 64;
    const int lane = tid & 63, w = tid >> 6;
    const int wr = w >> 1, wc = w & 1;
    const int r16 = lane & 15, g = lane >> 4;
    const int sr = tid >> 4;
    const int sc = (tid & 15) * 4;
    const float* cvb[4];
    bool aok[4];
    #pragma unroll
    for (int p = 0; p < 4; ++p) {
        int row = bm + sr + p * 16;
        aok[p] = row < M;
        int b = row / 196, pp = row % 196;
        int py = pp / 14, px = pp % 14;
        cvb[p] = X + (size_t)b * 150528 + (size_t)(py * 16) * 224 + px * 16;
    }
    float4 ra[4], rb[4];
    auto LOADT = [&](int k0) {
        int k = k0 + sc;
        int c = k >> 8, ii = (k >> 4) & 15, j = k & 15;
        size_t coff = (size_t)c * 50176 + ii * 224 + j;
        #pragma unroll
        for (int p = 0; p < 4; ++p) {
            ra[p] = aok[p] ? *(const float4*)(cvb[p] + coff) : make_float4(0.f, 0.f, 0.f, 0.f);
            rb[p] = *(const float4*)(W + (size_t)(bn + sr + p * 16) * K + k0 + sc);
        }
    };
    auto STORET = [&]() {
        #pragma unroll
        for (int p = 0; p < 4; ++p) {
            int r = sr + p * 16;
            float4 a4 = ra[p], b4 = rb[p];
            short4 ah, al, bh, bl;
            f2bf2(a4.x, ah.x, al.x); f2bf2(a4.y, ah.y, al.y);
            f2bf2(a4.z, ah.z, al.z); f2bf2(a4.w, ah.w, al.w);
            f2bf2(b4.x, bh.x, bl.x); f2bf2(b4.y, bh.y, bl.y);
            f2bf2(b4.z, bh.z, bl.z); f2bf2(b4.w, bh.w, bl.w);
            *(short4*)&Ah[r * LD2 + sc] = ah; *(short4*)&Al[r * LD2 + sc] = al;
            *(short4*)&Bh[r * LD2 + sc] = bh; *(short4*)&Bl[r * LD2 + sc] = bl;
        }
    };
    f32x4 acc[2][2] = {};
    auto COMPUTE = [&]() {
        #pragma unroll
        for (int kk = 0; kk < 2; ++kk) {
            bf16x8 afh[2], afl[2], bfh[2], bfl[2];
            #pragma unroll
            for (int i = 0; i < 2; ++i) {
                int off = (wr * 32 + i * 16 + r16) * LD2 + kk * 32 + g * 8;
                afh[i] = *(const bf16x8*)&Ah[off];
                afl[i] = *(const bf16x8*)&Al[off];
            }
            #pragma unroll
            for (int j = 0; j < 2; ++j) {
                int off = (wc * 32 + j * 16 + r16) * LD2 + kk * 32 + g * 8;
                bfh[j] = *(const bf16x8*)&Bh[off];
                bfl[j] = *(const bf16x8*)&Bl[off];
            }
            #pragma unroll
            for (int i = 0; i < 2; ++i)
                #pragma unroll
                for (int j = 0; j < 2; ++j) {
                    acc[i][j] = __builtin_amdgcn_mfma_f32_16x16x32_bf16(afl[i], bfh[j], acc[i][j], 0, 0, 0);
                    acc[i][j] = __builtin_amdgcn_mfma_f32_16x16x32_bf16(afh[i], bfl[j], acc[i][j], 0, 0, 0);
                    acc[i][j] = __builtin_amdgcn_mfma_f32_16x16x32_bf16(afh[i], bfh[j], acc[i][j], 0, 0, 0);
                }
        }
    };
    LOADT(0);
    STORET();
    __syncthreads();
    for (int k0 = 64; k0 < K; k0 += 64) {
        LOADT(k0);
        COMPUTE();
        __syncthreads();
        STORET();
        __syncthreads();
    }
    COMPUTE();
    #pragma unroll
    for (int i = 0; i < 2; ++i) {
        #pragma unroll
        for (int j = 0; j < 2; ++j) {
            int n = bn + wc * 32 + j * 16 + r16;
            int mbase = bm + wr * 32 + i * 16 + g * 4;
            #pragma unroll
            for (int r = 0; r < 4; ++r) {
                int m = mbase + r;
                if (m < M) {
                    int b = m / 196, pp = m % 196;
                    int t = b * NTOK + 1 + pp;
                    H[(size_t)t * DM + n] = acc[i][j][r] + pb[n] + pos[(size_t)(1 + pp) * DM + n];
                }
            }
        }
    }
    if (vb == 0) {
        for (int idx2 = tid; idx2 < NBATCH * DM; idx2 += 256) {
            int b = idx2 / DM, d = idx2 % DM;
            H[(size_t)(b * NTOK) * DM + d] = cls[d] + pos[d];
        }
    }
}

// ---------------- scores+softmax phase body ----------------
__device__ void scoresm_dev(int vb, float* smem,
                            const float* QKV, float* S)
{
    int z = vb / 7;
    int i0 = (vb % 7) * 32;
    int b = z / NHEAD, hh = z % NHEAD;
    float* qs = smem;             // [32][65]
    float* ks = smem + 2080;      // [32][65]
    float* srow = smem + 4160;    // [32][200]
    int tid = threadIdx.x;
    int r = tid >> 3, d0 = (tid & 7) * 8, c0 = (tid & 7) * 4, l8 = tid & 7;
    {
        float4 v0 = make_float4(0,0,0,0), v1 = v0;
        if (i0 + r < NTOK) {
            const float* qp = QKV + ((size_t)(b * NTOK + i0 + r)) * 1152 + hh * 64 + d0;
            v0 = *(const float4*)qp; v1 = *(const float4*)(qp + 4);
        }
        float* q = qs + r * 65 + d0;
        q[0]=v0.x; q[1]=v0.y; q[2]=v0.z; q[3]=v0.w;
        q[4]=v1.x; q[5]=v1.y; q[6]=v1.z; q[7]=v1.w;
    }
    if (l8 == 0) {
        srow[r * 200 + 197] = -1e30f; srow[r * 200 + 198] = -1e30f; srow[r * 200 + 199] = -1e30f;
    }
    for (int j0 = 0; j0 < NTOK; j0 += 32) {
        __syncthreads();
        {
            float4 v0 = make_float4(0,0,0,0), v1 = v0;
            if (j0 + r < NTOK) {
                const float* kp = QKV + ((size_t)(b * NTOK + j0 + r)) * 1152 + 384 + hh * 64 + d0;
                v0 = *(const float4*)kp; v1 = *(const float4*)(kp + 4);
            }
            float* k = ks + r * 65 + d0;
            k[0]=v0.x; k[1]=v0.y; k[2]=v0.z; k[3]=v0.w;
            k[4]=v1.x; k[5]=v1.y; k[6]=v1.z; k[7]=v1.w;
        }
        __syncthreads();
        float acc[4] = {0.f, 0.f, 0.f, 0.f};
        #pragma unroll 8
        for (int d = 0; d < 64; ++d) {
            float qv = qs[r * 65 + d];
            #pragma unroll
            for (int u = 0; u < 4; ++u) acc[u] += qv * ks[(c0 + u) * 65 + d];
        }
        #pragma unroll
        for (int u = 0; u < 4; ++u) {
            int j = j0 + c0 + u;
            if (j < NTOK) srow[r * 200 + j] = acc[u] * 0.125f;
        }
    }
    __syncthreads();
    float m = -1e30f;
    for (int c = l8; c < 200; c += 8) m = fmaxf(m, srow[r * 200 + c]);
    #pragma unroll
    for (int off = 1; off < 8; off <<= 1) m = fmaxf(m, __shfl_xor(m, off));
    float s = 0.f;
    for (int c = l8; c < 200; c += 8) {
        float e = expf(srow[r * 200 + c] - m);
        srow[r * 200 + c] = e;
        s += e;
    }
    #pragma unroll
    for (int off = 1; off < 8; off <<= 1) s += __shfl_xor(s, off);
    float invs = 1.f / s;
    int i = i0 + r;
    if (i < NTOK) {
        float* sp = S + ((size_t)z * NTOK + i) * NTOK;
        for (int c = l8; c < NTOK; c += 8) sp[c] = srow[r * 200 + c] * invs;
    }
}

// ---------------- PV phase body ----------------
__device__ void pv_dev(int vb, float* smem,
                       const float* S, const float* QKV, float* AO)
{
    int z = vb / 7;
    int i0 = (vb % 7) * 32;
    int b = z / NHEAD, hh = z % NHEAD;
    float* ps = smem;            // [32][33]
    float* vs = smem + 1056;     // [32][65]
    int tid = threadIdx.x;
    int r = tid >> 3;
    int c4 = (tid & 7) * 4;
    int d0 = (tid & 7) * 8;
    float acc[8] = {};
    for (int k0 = 0; k0 < NTOK; k0 += 32) {
        #pragma unroll
        for (int u = 0; u < 4; ++u) {
            int i = i0 + r, j = k0 + c4 + u;
            ps[r * 33 + c4 + u] = (i < NTOK && j < NTOK) ? S[((size_t)z * NTOK + i) * NTOK + j] : 0.f;
        }
        {
            float4 v0 = make_float4(0,0,0,0), v1 = v0;
            if (k0 + r < NTOK) {
                const float* vp = QKV + ((size_t)(b * NTOK + k0 + r)) * 1152 + 768 + hh * 64 + d0;
                v0 = *(const float4*)vp; v1 = *(const float4*)(vp + 4);
            }
            float* v = vs + r * 65 + d0;
            v[0]=v0.x; v[1]=v0.y; v[2]=v0.z; v[3]=v0.w;
            v[4]=v1.x; v[5]=v1.y; v[6]=v1.z; v[7]=v1.w;
        }
        __syncthreads();
        #pragma unroll 8
        for (int kk = 0; kk < 32; ++kk) {
            float pw = ps[r * 33 + kk];
            #pragma unroll
            for (int j = 0; j < 8; ++j) acc[j] += pw * vs[kk * 65 + d0 + j];
        }
        __syncthreads();
    }
    int i = i0 + r;
    if (i < NTOK) {
        float* op = AO + (size_t)(b * NTOK + i) * DM + hh * 64 + d0;
        #pragma unroll
        for (int j = 0; j < 8; ++j) op[j] = acc[j];
    }
}

// ---------------- MoE routing phase body ----------------
__device__ void route_dev(int vb, const float* H, float* lnstat,
                          const float* lnw, const float* lnb, const float* GW,
                          int* eidx, float* egate)
{
    int t = vb * 4 + (threadIdx.x >> 6);
    if (t >= TT) return;
    int lane = threadIdx.x & 63;
    const float* x = H + (size_t)t * DM;
    float v[6];
    float s = 0.f, ss = 0.f;
    #pragma unroll
    for (int i = 0; i < 6; ++i) {
        v[i] = x[lane + i * 64];
        s += v[i];
        ss += v[i] * v[i];
    }
    #pragma unroll
    for (int off = 32; off; off >>= 1) { s += __shfl_xor(s, off); ss += __shfl_xor(ss, off); }
    float mean = s * (1.f / 384.f);
    float var = ss * (1.f / 384.f) - mean * mean;
    float inv = rsqrtf(var + 1e-6f);
    if (lane == 0) { lnstat[2 * t] = mean; lnstat[2 * t + 1] = inv; }
    float l8v[NEXP] = {};
    #pragma unroll
    for (int i = 0; i < 6; ++i) {
        int d = lane + i * 64;
        float yv = (v[i] - mean) * inv * lnw[d] + lnb[d];
        const float* g = GW + (size_t)d * NEXP;
        #pragma unroll
        for (int e = 0; e < NEXP; ++e) l8v[e] += yv * g[e];
    }
    #pragma unroll
    for (int e = 0; e < NEXP; ++e) {
        float vv = l8v[e];
        #pragma unroll
        for (int off = 32; off; off >>= 1) vv += __shfl_xor(vv, off);
        l8v[e] = vv;
    }
    if (lane == 0) {
        int b0 = 0;
        #pragma unroll
        for (int e = 1; e < NEXP; ++e) if (l8v[e] > l8v[b0]) b0 = e;
        int b1 = -1;
        #pragma unroll
        for (int e = 0; e < NEXP; ++e) if (e != b0 && (b1 < 0 || l8v[e] > l8v[b1])) b1 = e;
        float e1 = expf(l8v[b1] - l8v[b0]);
        float denom = 1.f + e1;
        eidx[2 * t] = b0; eidx[2 * t + 1] = b1;
        egate[2 * t] = 1.f / denom; egate[2 * t + 1] = e1 / denom;
    }
}

// ---------------- pscatter phase body (single block) ----------------
__device__ void pscatter_dev(float* smem, int* cnt, int* basep,
                             const int* eidx, const float* egate,
                             int* slot_tok, float* slot_gate)
{
    int* hist = (int*)smem;
    int* bp = hist + NEXP;
    int* fl = bp + NEXP;
    int tid = threadIdx.x;
    if (tid < NEXP) { hist[tid] = 0; fl[tid] = 0; }
    __syncthreads();
    for (int i = tid; i < 2 * TT; i += 256) atomicAdd(&hist[eidx[i]], 1);
    __syncthreads();
    if (tid == 0) {
        int s = 0;
        for (int e = 0; e < NEXP; ++e) { bp[e] = s; s += hist[e]; }
    }
    __syncthreads();
    if (tid < NEXP) { cnt[tid] = hist[tid]; basep[tid] = bp[tid]; }
    for (int t = tid; t < TT; t += 256) {
        #pragma unroll
        for (int k = 0; k < 2; ++k) {
            int e = eidx[2 * t + k];
            int pos = atomicAdd(&fl[e], 1);
            int s = bp[e] + pos;
            slot_tok[s] = t;
            slot_gate[s] = egate[2 * t + k];
        }
    }
}

// ---------------- MoE FFN1 phase body ----------------
__device__ void moe1_dev(int vb, float* smem,
                         const float* H, const float* lnstat,
                         const float* lnw, const float* lnb,
                         const float* W1, const float* B1,
                         const int* slot_tok, const int* cnt, const int* basep,
                         float* HID)
{
    const int e = vb & 7;
    const int idx = vb >> 3;
    const int mt = idx % 13;
    const int nt = idx / 13;
    const int c = cnt[e];
    const int r0 = mt * 64;
    if (r0 >= c) return;
    const int sbase = basep[e];
    const int n0 = nt * 64;
    const float* W = W1 + (size_t)e * DM * HM;
    const float* B1e = B1 + (size_t)e * HM;
    short* Ah = (short*)smem;
    short* Al = Ah + 64 * LD2;
    short* Bh = Al + 64 * LD2;
    short* Bl = Bh + 64 * LD2;
    const int tid = threadIdx.x;
    const int lane = tid & 63, w = tid >> 6;
    const int wr = w >> 1, wc = w & 1;
    const int r16 = lane & 15, g = lane >> 4;
    const int sr = tid >> 4, sc = (tid & 15) * 4;
    const int kq = (tid >> 4) * 4;
    int tokp[4];
    float am4[4], ai4[4];
    #pragma unroll
    for (int p = 0; p < 4; ++p) {
        int m = r0 + sr + p * 16;
        tokp[p] = (m < c) ? slot_tok[sbase + m] : -1;
        am4[p] = 0.f; ai4[p] = 1.f;
        if (tokp[p] >= 0) { am4[p] = lnstat[2 * tokp[p]]; ai4[p] = lnstat[2 * tokp[p] + 1]; }
    }
    f32x4 acc[2][2] = {};
    for (int k0 = 0; k0 < DM; k0 += 64) {
        float4 lw4 = *(const float4*)(lnw + k0 + sc);
        float4 lb4 = *(const float4*)(lnb + k0 + sc);
        #pragma unroll
        for (int p = 0; p < 4; ++p) {
            int r = sr + p * 16;
            float4 a4 = make_float4(0.f, 0.f, 0.f, 0.f);
            if (tokp[p] >= 0) {
                a4 = *(const float4*)(H + (size_t)tokp[p] * DM + k0 + sc);
                a4.x = (a4.x - am4[p]) * ai4[p] * lw4.x + lb4.x;
                a4.y = (a4.y - am4[p]) * ai4[p] * lw4.y + lb4.y;
                a4.z = (a4.z - am4[p]) * ai4[p] * lw4.z + lb4.z;
                a4.w = (a4.w - am4[p]) * ai4[p] * lw4.w + lb4.w;
            }
            short4 ah, al;
            f2bf2(a4.x, ah.x, al.x); f2bf2(a4.y, ah.y, al.y);
            f2bf2(a4.z, ah.z, al.z); f2bf2(a4.w, ah.w, al.w);
            *(short4*)&Ah[r * LD2 + sc] = ah; *(short4*)&Al[r * LD2 + sc] = al;
        }
        {
            float4 b4[4];
            #pragma unroll
            for (int i = 0; i < 4; ++i)
                b4[i] = *(const float4*)(W + (size_t)(k0 + kq + i) * HM + n0 + sc);
            float col[4][4] = {
                { b4[0].x, b4[1].x, b4[2].x, b4[3].x },
                { b4[0].y, b4[1].y, b4[2].y, b4[3].y },
                { b4[0].z, b4[1].z, b4[2].z, b4[3].z },
                { b4[0].w, b4[1].w, b4[2].w, b4[3].w } };
            #pragma unroll
            for (int u = 0; u < 4; ++u) {
                short4 hh, ll;
                f2bf2(col[u][0], hh.x, ll.x); f2bf2(col[u][1], hh.y, ll.y);
                f2bf2(col[u][2], hh.z, ll.z); f2bf2(col[u][3], hh.w, ll.w);
                *(short4*)&Bh[(sc + u) * LD2 + kq] = hh;
                *(short4*)&Bl[(sc + u) * LD2 + kq] = ll;
            }
        }
        __syncthreads();
        #pragma unroll
        for (int kk = 0; kk < 2; ++kk) {
            bf16x8 afh[2], afl[2], bfh[2], bfl[2];
            #pragma unroll
            for (int i = 0; i < 2; ++i) {
                int off = (wr * 32 + i * 16 + r16) * LD2 + kk * 32 + g * 8;
                afh[i] = *(const bf16x8*)&Ah[off];
                afl[i] = *(const bf16x8*)&Al[off];
            }
            #pragma unroll
            for (int j = 0; j < 2; ++j) {
                int off = (wc * 32 + j * 16 + r16) * LD2 + kk * 32 + g * 8;
                bfh[j] = *(const bf16x8*)&Bh[off];
                bfl[j] = *(const bf16x8*)&Bl[off];
            }
            #pragma unroll
            for (int i = 0; i < 2; ++i)
                #pragma unroll
                for (int j = 0; j < 2; ++j) {
                    acc[i][j] = __builtin_amdgcn_mfma_f32_16x16x32_bf16(afl[i], bfh[j], acc[i][j], 0, 0, 0);
                    acc[i][j] = __builtin_amdgcn_mfma_f32_16x16x32_bf16(afh[i], bfl[j], acc[i][j], 0, 0, 0);
                    acc[i][j] = __builtin_amdgcn_mfma_f32_16x16x32_bf16(afh[i], bfh[j], acc[i][j], 0, 0, 0);
                }
        }
        __syncthreads();
    }
    #pragma unroll
    for (int i = 0; i < 2; ++i) {
        #pragma unroll
        for (int j = 0; j < 2; ++j) {
            int n = n0 + wc * 32 + j * 16 + r16;
            float bb = B1e[n];
            #pragma unroll
            for (int r = 0; r < 4; ++r) {
                int m = r0 + wr * 32 + i * 16 + g * 4 + r;
                if (m < c)
                    HID[(size_t)(sbase + m) * HM + n] = gelu_f(acc[i][j][r] + bb);
            }
        }
    }
}

// ---------------- MoE FFN2 phase body ----------------
__device__ void moe2_dev(int vb, float* smem,
                         const float* HID, const float* W2, const float* B2,
                         const int* cnt, const int* basep,
                         const int* slot_tok, const float* slot_gate,
                         float* H)
{
    const int e = vb & 7;
    const int idx = vb >> 3;
    const int mt = idx % 13;
    const int rest = idx / 13;
    const int nt = rest % 6;
    const int ks = rest / 6;
    const int c = cnt[e];
    const int r0 = mt * 64;
    if (r0 >= c) return;
    const int sbase = basep[e];
    const int n0 = nt * 64;
    const int kbase = ks * 384;
    const float* W = W2 + (size_t)e * HM * DM + (size_t)kbase * DM;
    const float* B2e = B2 + (size_t)e * DM;
    short* Ah = (short*)smem;
    short* Al = Ah + 64 * LD2;
    short* Bh = Al + 64 * LD2;
    short* Bl = Bh + 64 * LD2;
    const int tid = threadIdx.x;
    const int lane = tid & 63, w = tid >> 6;
    const int wr = w >> 1, wc = w & 1;
    const int r16 = lane & 15, g = lane >> 4;
    const int sr = tid >> 4, sc = (tid & 15) * 4;
    const int kq = (tid >> 4) * 4;
    f32x4 acc[2][2] = {};
    for (int k0 = 0; k0 < 384; k0 += 64) {
        #pragma unroll
        for (int p = 0; p < 4; ++p) {
            int r = sr + p * 16;
            int m = r0 + r;
            float4 a4 = make_float4(0.f, 0.f, 0.f, 0.f);
            if (m < c) a4 = *(const float4*)(HID + (size_t)(sbase + m) * HM + kbase + k0 + sc);
            short4 ah, al;
            f2bf2(a4.x, ah.x, al.x); f2bf2(a4.y, ah.y, al.y);
            f2bf2(a4.z, ah.z, al.z); f2bf2(a4.w, ah.w, al.w);
            *(short4*)&Ah[r * LD2 + sc] = ah; *(short4*)&Al[r * LD2 + sc] = al;
        }
        {
            float4 b4[4];
            #pragma unroll
            for (int i = 0; i < 4; ++i)
                b4[i] = *(const float4*)(W + (size_t)(k0 + kq + i) * DM + n0 + sc);
            float col[4][4] = {
                { b4[0].x, b4[1].x, b4[2].x, b4[3].x },
                { b4[0].y, b4[1].y, b4[2].y, b4[3].y },
                { b4[0].z, b4[1].z, b4[2].z, b4[3].z },
                { b4[0].w, b4[1].w, b4[2].w, b4[3].w } };
            #pragma unroll
            for (int u = 0; u < 4; ++u) {
                short4 hh, ll;
                f2bf2(col[u][0], hh.x, ll.x); f2bf2(col[u][1], hh.y, ll.y);
                f2bf2(col[u][2], hh.z, ll.z); f2bf2(col[u][3], hh.w, ll.w);
                *(short4*)&Bh[(sc + u) * LD2 + kq] = hh;
                *(short4*)&Bl[(sc + u) * LD2 + kq] = ll;
            }
        }
        __syncthreads();
        #pragma unroll
        for (int kk = 0; kk < 2; ++kk) {
            bf16x8 afh[2], afl[2], bfh[2], bfl[2];
            #pragma unroll
            for (int i = 0; i < 2; ++i) {
                int off = (wr * 32 + i * 16 + r16) * LD2 + kk * 32 + g * 8;
                afh[i] = *(const bf16x8*)&Ah[off];
                afl[i] = *(const bf16x8*)&Al[off];
            }
            #pragma unroll
            for (int j = 0; j < 2; ++j) {
                int off = (wc * 32 + j * 16 + r16) * LD2 + kk * 32 + g * 8;
                bfh[j] = *(const bf16x8*)&Bh[off];
                bfl[j] = *(const bf16x8*)&Bl[off];
            }
            #pragma unroll
            for (int i = 0; i < 2; ++i)
                #pragma unroll
                for (int j = 0; j < 2; ++j) {
                    acc[i][j] = __builtin_amdgcn_mfma_f32_16x16x32_bf16(afl[i], bfh[j], acc[i][j], 0, 0, 0);
                    acc[i][j] = __builtin_amdgcn_mfma_f32_16x16x32_bf16(afh[i], bfl[j], acc[i][j], 0, 0, 0);
                    acc[i][j] = __builtin_amdgcn_mfma_f32_16x16x32_bf16(afh[i], bfh[j], acc[i][j], 0, 0, 0);
                }
        }
        __syncthreads();
    }
    #pragma unroll
    for (int i = 0; i < 2; ++i) {
        #pragma unroll
        for (int j = 0; j < 2; ++j) {
            int n = n0 + wc * 32 + j * 16 + r16;
            float bb = (ks == 0) ? B2e[n] : 0.f;
            #pragma unroll
            for (int r = 0; r < 4; ++r) {
                int m = r0 + wr * 32 + i * 16 + g * 4 + r;
                if (m < c) {
                    int tok = slot_tok[sbase + m];
                    float gt = slot_gate[sbase + m];
                    atomicAdd(&H[(size_t)tok * DM + n], gt * (acc[i][j][r] + bb));
                }
            }
        }
    }
}

// ---------------- final LN phase body (4 tokens / vblock) ----------------
__device__ void lnf_dev(int vb, const float* X, const float* w,
                        const float* b, float* Y)
{
    int t = vb * 4 + (threadIdx.x >> 6);
    if (t >= TT) return;
    int lane = threadIdx.x & 63;
    const float* x = X + (size_t)t * DM;
    float v[6];
    float s = 0.f, ss = 0.f;
    #pragma unroll
    for (int i = 0; i < 6; ++i) {
        v[i] = x[lane + i * 64];
        s += v[i];
        ss += v[i] * v[i];
    }
    #pragma unroll
    for (int off = 32; off; off >>= 1) { s += __shfl_xor(s, off); ss += __shfl_xor(ss, off); }
    float mean = s * (1.f / 384.f);
    float var = ss * (1.f / 384.f) - mean * mean;
    float inv = rsqrtf(var + 1e-6f);
    float* y = Y + (size_t)t * DM;
    #pragma unroll
    for (int i = 0; i < 6; ++i) {
        int d = lane + i * 64;
        y[d] = (v[i] - mean) * inv * w[d] + b[d];
    }
}

// =====================================================================
// Cooperative megakernel: the whole forward pass with grid-wide syncs.
// =====================================================================
__global__ void __launch_bounds__(256) k_mega(MParams p) {
    cg::grid_group gg = cg::this_grid();
    __shared__ float smem[10560];   // 42240 B union of all phase layouts

    for (int vb = blockIdx.x; vb < 96; vb += gridDim.x) {
        patch_dev(vb, smem, p.x, p.patch_w, p.patch_b, p.cls_token, p.pos_embed, p.h);
        __syncthreads();
    }
    gg.sync();

    for (int l = 0; l < 12; ++l) {
        int j = l >> 1;
        // qkv (LN fused)
        for (int vb = blockIdx.x; vb < 312; vb += gridDim.x) {
            gemm_dev(vb, smem, p.h, p.qkv_w + (size_t)l * 1152 * DM, p.qkv_b + l * 1152,
                     p.qkvb, TT, 1152, DM, 8, 13, 18, 1, 1,
                     p.ln1_w + l * DM, p.ln1_b + l * DM);
            __syncthreads();
        }
        gg.sync();
        for (int vb = blockIdx.x; vb < 168; vb += gridDim.x) {
            scoresm_dev(vb, smem, p.qkvb, p.S);
            __syncthreads();
        }
        gg.sync();
        for (int vb = blockIdx.x; vb < 168; vb += gridDim.x) {
            pv_dev(vb, smem, p.S, p.qkvb, p.attno);
            __syncthreads();
        }
        gg.sync();
        // proj: K-split 2 atomic into h
        for (int vb = blockIdx.x; vb < 192; vb += gridDim.x) {
            gemm_dev(vb, smem, p.attno, p.proj_w + (size_t)l * DM * DM, p.proj_b + l * DM,
                     p.h, TT, DM, DM, 16, 13, 6, 0, 2, nullptr, nullptr);
            __syncthreads();
        }
        gg.sync();
        if ((l & 1) == 0) {
            for (int vb = blockIdx.x; vb < 312; vb += gridDim.x) {
                gemm_dev(vb, smem, p.h, p.fc1_w + (size_t)j * HM * DM, p.fc1_b + j * HM,
                         p.hid, TT, HM, DM, 8, 13, 24, 1, 1,
                         p.ln2_w + l * DM, p.ln2_b + l * DM);
                __syncthreads();
            }
            gg.sync();
            for (int vb = blockIdx.x; vb < 384; vb += gridDim.x) {
                gemm_dev(vb, smem, p.hid, p.fc2_w + (size_t)j * DM * HM, p.fc2_b + j * DM,
                         p.h, TT, DM, HM, 16 | 32, 13, 6, 0, 4, nullptr, nullptr);
                __syncthreads();
            }
            gg.sync();
        } else {
            for (int vb = blockIdx.x; vb < 197; vb += gridDim.x)
                route_dev(vb, p.h, p.lnstat, p.ln2_w + l * DM, p.ln2_b + l * DM,
                          p.gate_w + (size_t)j * DM * NEXP, p.eidx, p.egate);
            gg.sync();
            if (blockIdx.x == 0)
                pscatter_dev(smem, p.cnt, p.basep, p.eidx, p.egate, p.slot_tok, p.slot_gate);
            gg.sync();
            for (int vb = blockIdx.x; vb < 2496; vb += gridDim.x) {
                moe1_dev(vb, smem, p.h, p.lnstat, p.ln2_w + l * DM, p.ln2_b + l * DM,
                         p.moe_w1 + (size_t)j * NEXP * DM * HM, p.moe_b1 + (size_t)j * NEXP * HM,
                         p.slot_tok, p.cnt, p.basep, p.moehid);
                __syncthreads();
            }
            gg.sync();
            for (int vb = blockIdx.x; vb < 2496; vb += gridDim.x) {
                moe2_dev(vb, smem, p.moehid, p.moe_w2 + (size_t)j * NEXP * HM * DM,
                         p.moe_b2 + (size_t)j * NEXP * DM,
                         p.cnt, p.basep, p.slot_tok, p.slot_gate, p.h);
                __syncthreads();
            }
            gg.sync();
        }
    }
    for (int vb = blockIdx.x; vb < 197; vb += gridDim.x)
        lnf_dev(vb, p.h, p.lnf_w, p.lnf_b, p.out);
}

extern "C" void kernel_launch(void* const* d_in, const int* in_sizes, int n_in,
                              void* d_out, int out_size, void* d_ws, size_t ws_size,
                              hipStream_t stream) {
    MParams p;
    p.x         = (const float*)d_in[0];
    p.patch_w   = (const float*)d_in[1];
    p.patch_b   = (const float*)d_in[2];
    p.cls_token = (const float*)d_in[3];
    p.pos_embed = (const float*)d_in[4];
    p.ln1_w     = (const float*)d_in[5];
    p.ln1_b     = (const float*)d_in[6];
    p.qkv_w     = (const float*)d_in[7];
    p.qkv_b     = (const float*)d_in[8];
    p.proj_w    = (const float*)d_in[9];
    p.proj_b    = (const float*)d_in[10];
    p.ln2_w     = (const float*)d_in[11];
    p.ln2_b     = (const float*)d_in[12];
    p.fc1_w     = (const float*)d_in[13];
    p.fc1_b     = (const float*)d_in[14];
    p.fc2_w     = (const float*)d_in[15];
    p.fc2_b     = (const float*)d_in[16];
    p.gate_w    = (const float*)d_in[17];
    p.moe_w1    = (const float*)d_in[18];
    p.moe_b1    = (const float*)d_in[19];
    p.moe_w2    = (const float*)d_in[20];
    p.moe_b2    = (const float*)d_in[21];
    p.lnf_w     = (const float*)d_in[22];
    p.lnf_b     = (const float*)d_in[23];
    p.out = (float*)d_out;

    float* wsf = (float*)d_ws;
    float* regA = wsf;                       // moehid: 1576 rows x 1536
    p.moehid = regA;
    p.h     = regA + 2420736;
    float* spare = p.h + 302592;
    p.qkvb  = spare + 302592;
    p.attno = p.qkvb + 907776;
    float* regC = p.attno + 302592;          // S / hid alias
    p.S   = regC;
    p.hid = regC;
    p.egate = regC + 1210368;
    int* ib = (int*)(p.egate + 1576);
    p.eidx     = ib;
    p.slot_tok = ib + 1576;
    p.cnt      = ib + 4728;
    p.basep    = ib + 4736;
    p.lnstat   = (float*)(ib + 4752);
    p.slot_gate = p.lnstat + 1576;

    int nb = 0;
    hipOccupancyMaxActiveBlocksPerMultiprocessor(&nb, k_mega, 256, 0);
    if (nb < 1) nb = 1;
    int grid = nb * 256;                     // 256 CUs on MI355X
    if (grid > 512) grid = 512;
    void* args[] = { (void*)&p };
    hipLaunchCooperativeKernel((void*)k_mega, dim3(grid), dim3(256), args, 0, stream);
}

// Round 18
// 1669.569 us; speedup vs baseline: 2.7450x; 2.7450x over previous
//
#include <hip/hip_runtime.h>
#include <math.h>

#define NBATCH 4
#define NTOK 197
#define TT 788            // NBATCH*NTOK
#define DM 384
#define HM 1536
#define NHEAD 6
#define NEXP 8
#define LD2 72            // LDS row stride (shorts) for 64-k tiles (+8 pad)
#define MOUTSZ (TT * 2 * DM)

typedef __attribute__((ext_vector_type(8))) short bf16x8;
typedef __attribute__((ext_vector_type(4))) float f32x4;

__device__ __forceinline__ void f2bf2(float x, short& hi, short& lo) {
    unsigned u = __float_as_uint(x);
    unsigned uh = u + (0x7fffu + ((u >> 16) & 1u));
    hi = (short)(uh >> 16);
    float hf = __uint_as_float(uh & 0xffff0000u);
    float r = x - hf;
    unsigned v = __float_as_uint(r);
    lo = (short)((v + (0x7fffu + ((v >> 16) & 1u))) >> 16);
}
__device__ __forceinline__ float gelu_f(float x) {
    return 0.5f * x * (1.0f + erff(x * 0.7071067811865475f));
}

// ---------------- im2col ----------------
__global__ void k_im2col(const float* __restrict__ X, float* __restrict__ P) {
    int p = blockIdx.x;
    int b = p / 196, pp = p % 196;
    int py = pp / 14, px = pp % 14;
    const float* xb = X + (size_t)b * 3 * 224 * 224;
    float* dst = P + (size_t)p * 768;
    for (int idx = threadIdx.x; idx < 768; idx += 256) {
        int c = idx >> 8;
        int i = (idx >> 4) & 15;
        int j = idx & 15;
        dst[idx] = xb[((size_t)c * 224 + py * 16 + i) * 224 + px * 16 + j];
    }
}

// ---------------- assemble tokens ----------------
__global__ void k_assemble(const float* __restrict__ PO, const float* __restrict__ pb,
                           const float* __restrict__ cls, const float* __restrict__ pos,
                           float* __restrict__ H) {
    int t = blockIdx.x;
    int b = t / NTOK, n = t % NTOK;
    for (int d = threadIdx.x; d < DM; d += 128) {
        float v;
        if (n == 0) v = cls[d];
        else v = PO[((size_t)b * 196 + (n - 1)) * DM + d] + pb[d];
        H[(size_t)t * DM + d] = v + pos[(size_t)n * DM + d];
    }
}

// ---------------- layernorm (final output only) ----------------
__global__ void k_ln(const float* __restrict__ X, const float* __restrict__ w,
                     const float* __restrict__ b, float* __restrict__ Y) {
    int t = blockIdx.x, lane = threadIdx.x;
    const float* x = X + (size_t)t * DM;
    float v[6];
    float s = 0.f;
    #pragma unroll
    for (int i = 0; i < 6; ++i) { v[i] = x[lane + i * 64]; s += v[i]; }
    #pragma unroll
    for (int off = 32; off; off >>= 1) s += __shfl_xor(s, off);
    float mean = s * (1.f / 384.f);
    float q = 0.f;
    #pragma unroll
    for (int i = 0; i < 6; ++i) { float d = v[i] - mean; q += d * d; }
    #pragma unroll
    for (int off = 32; off; off >>= 1) q += __shfl_xor(q, off);
    float inv = rsqrtf(q * (1.f / 384.f) + 1e-6f);
    float* y = Y + (size_t)t * DM;
    #pragma unroll
    for (int i = 0; i < 6; ++i) {
        int d = lane + i * 64;
        y[d] = (v[i] - mean) * inv * w[d] + b[d];
    }
}

// =====================================================================
// Pipelined split-precision MFMA GEMM: C = A@W^T, BK=64.
// flags: 1=gelu-out, 2=accumulate, 8=LN-on-A (stats in-block; K==384),
//        16=atomicAdd output (K-split partials; bias added by ks==0 only).
// Flat grid + XCD grouping; ksplit folds into the flat grid index.
// =====================================================================
__global__ __launch_bounds__(256) void k_gemm_mfma(
    const float* __restrict__ A, const float* __restrict__ W,
    const float* __restrict__ bias, float* __restrict__ C,
    int M, int N, int K, int flags, int MT, int NT, int wprot, int ksplit,
    const float* __restrict__ lnw, const float* __restrict__ lnb)
{
    int mt, nt, ks = 0;
    {
        int lane8 = blockIdx.x & 7;
        int idx = blockIdx.x >> 3;
        if (ksplit > 1) { ks = idx % ksplit; idx /= ksplit; }
        if (wprot) {
            mt = idx % MT;
            nt = lane8 + 8 * (idx / MT);
            if (nt >= NT) return;
        } else {
            nt = idx % NT;
            mt = lane8 + 8 * (idx / NT);
            if (mt >= MT) return;
        }
    }
    const int Ks = K / ksplit;
    const float* Ab = A + (size_t)ks * Ks;
    const float* Wb = W + (size_t)ks * Ks;
    __shared__ short Ah[64 * LD2], Al[64 * LD2], Bh[64 * LD2], Bl[64 * LD2];
    const int bm = mt * 64, bn = nt * 64;
    const int tid = threadIdx.x;
    const int lane = tid & 63, w = tid >> 6;
    const int wr = w >> 1, wc = w & 1;
    const int r16 = lane & 15, g = lane >> 4;
    const int sr = tid >> 4;          // 0..15
    const int sc = (tid & 15) * 4;    // 0..60
    const bool doln = (flags & 8) != 0;
    float am[4], ai[4];
    #pragma unroll
    for (int p = 0; p < 4; ++p) { am[p] = 0.f; ai[p] = 1.f; }
    if (doln) {
        int j = tid & 15;
        #pragma unroll
        for (int p = 0; p < 4; ++p) {
            int r = bm + sr + p * 16;
            if (r < M) {
                const float* xr = A + (size_t)r * K;
                float s = 0.f, ss = 0.f;
                #pragma unroll
                for (int i = 0; i < 6; ++i) {
                    float4 v = *(const float4*)(xr + j * 4 + i * 64);
                    s += v.x + v.y + v.z + v.w;
                    ss += v.x * v.x + v.y * v.y + v.z * v.z + v.w * v.w;
                }
                #pragma unroll
                for (int off = 1; off < 16; off <<= 1) {
                    s += __shfl_xor(s, off);
                    ss += __shfl_xor(ss, off);
                }
                float mean = s * (1.f / 384.f);
                float var = ss * (1.f / 384.f) - mean * mean;
                am[p] = mean;
                ai[p] = rsqrtf(var + 1e-6f);
            }
        }
    }
    float4 ra[4], rb[4], lw4, lb4;
    auto LOADT = [&](int k0) {
        if (doln) {
            lw4 = *(const float4*)(lnw + k0 + sc);
            lb4 = *(const float4*)(lnb + k0 + sc);
        }
        #pragma unroll
        for (int p = 0; p < 4; ++p) {
            int r = sr + p * 16;
            ra[p] = make_float4(0.f, 0.f, 0.f, 0.f);
            if (bm + r < M) ra[p] = *(const float4*)(Ab + (size_t)(bm + r) * K + k0 + sc);
            rb[p] = *(const float4*)(Wb + (size_t)(bn + r) * K + k0 + sc);
        }
    };
    auto STORET = [&]() {
        #pragma unroll
        for (int p = 0; p < 4; ++p) {
            int r = sr + p * 16;
            float4 a4 = ra[p];
            if (doln) {
                a4.x = (a4.x - am[p]) * ai[p] * lw4.x + lb4.x;
                a4.y = (a4.y - am[p]) * ai[p] * lw4.y + lb4.y;
                a4.z = (a4.z - am[p]) * ai[p] * lw4.z + lb4.z;
                a4.w = (a4.w - am[p]) * ai[p] * lw4.w + lb4.w;
            }
            float4 b4 = rb[p];
            short4 ah, al, bh, bl;
            f2bf2(a4.x, ah.x, al.x); f2bf2(a4.y, ah.y, al.y);
            f2bf2(a4.z, ah.z, al.z); f2bf2(a4.w, ah.w, al.w);
            f2bf2(b4.x, bh.x, bl.x); f2bf2(b4.y, bh.y, bl.y);
            f2bf2(b4.z, bh.z, bl.z); f2bf2(b4.w, bh.w, bl.w);
            *(short4*)&Ah[r * LD2 + sc] = ah; *(short4*)&Al[r * LD2 + sc] = al;
            *(short4*)&Bh[r * LD2 + sc] = bh; *(short4*)&Bl[r * LD2 + sc] = bl;
        }
    };
    f32x4 acc[2][2] = {};
    auto COMPUTE = [&]() {
        #pragma unroll
        for (int kk = 0; kk < 2; ++kk) {
            bf16x8 afh[2], afl[2], bfh[2], bfl[2];
            #pragma unroll
            for (int i = 0; i < 2; ++i) {
                int off = (wr * 32 + i * 16 + r16) * LD2 + kk * 32 + g * 8;
                afh[i] = *(const bf16x8*)&Ah[off];
                afl[i] = *(const bf16x8*)&Al[off];
            }
            #pragma unroll
            for (int j = 0; j < 2; ++j) {
                int off = (wc * 32 + j * 16 + r16) * LD2 + kk * 32 + g * 8;
                bfh[j] = *(const bf16x8*)&Bh[off];
                bfl[j] = *(const bf16x8*)&Bl[off];
            }
            #pragma unroll
            for (int i = 0; i < 2; ++i)
                #pragma unroll
                for (int j = 0; j < 2; ++j) {
                    acc[i][j] = __builtin_amdgcn_mfma_f32_16x16x32_bf16(afl[i], bfh[j], acc[i][j], 0, 0, 0);
                    acc[i][j] = __builtin_amdgcn_mfma_f32_16x16x32_bf16(afh[i], bfl[j], acc[i][j], 0, 0, 0);
                    acc[i][j] = __builtin_amdgcn_mfma_f32_16x16x32_bf16(afh[i], bfh[j], acc[i][j], 0, 0, 0);
                }
        }
    };
    LOADT(0);
    STORET();
    __syncthreads();
    for (int k0 = 64; k0 < Ks; k0 += 64) {
        LOADT(k0);        // global loads in flight during compute
        COMPUTE();
        __syncthreads();  // all LDS reads done
        STORET();
        __syncthreads();
    }
    COMPUTE();
    #pragma unroll
    for (int i = 0; i < 2; ++i) {
        #pragma unroll
        for (int j = 0; j < 2; ++j) {
            int n = bn + wc * 32 + j * 16 + r16;
            float bb = (bias && ks == 0) ? bias[n] : 0.f;
            int mbase = bm + wr * 32 + i * 16 + g * 4;
            #pragma unroll
            for (int r = 0; r < 4; ++r) {
                int m = mbase + r;
                if (m < M) {
                    float v = acc[i][j][r] + bb;
                    float* cp = C + (size_t)m * N + n;
                    if (flags & 16) {
                        atomicAdd(cp, v);
                    } else {
                        if (flags & 1) v = gelu_f(v);
                        if (flags & 2) v += *cp;
                        *cp = v;
                    }
                }
            }
        }
    }
}

// =====================================================================
// Fused scores+softmax: writes normalized P into S. grid (7, 24).
// =====================================================================
__global__ __launch_bounds__(256) void k_scoresm(const float* __restrict__ QKV,
                                                 float* __restrict__ S) {
    int z = blockIdx.y;
    int b = z / NHEAD, hh = z % NHEAD;
    int i0 = blockIdx.x * 32;
    __shared__ float qs[32][65];
    __shared__ float ks[32][65];
    __shared__ float srow[32][200];
    int tid = threadIdx.x;
    int r = tid >> 3, d0 = (tid & 7) * 8, c0 = (tid & 7) * 4, l8 = tid & 7;
    {
        float4 v0 = make_float4(0,0,0,0), v1 = v0;
        if (i0 + r < NTOK) {
            const float* qp = QKV + ((size_t)(b * NTOK + i0 + r)) * 1152 + hh * 64 + d0;
            v0 = *(const float4*)qp; v1 = *(const float4*)(qp + 4);
        }
        qs[r][d0+0]=v0.x; qs[r][d0+1]=v0.y; qs[r][d0+2]=v0.z; qs[r][d0+3]=v0.w;
        qs[r][d0+4]=v1.x; qs[r][d0+5]=v1.y; qs[r][d0+6]=v1.z; qs[r][d0+7]=v1.w;
    }
    if (l8 == 0) { srow[r][197] = -1e30f; srow[r][198] = -1e30f; srow[r][199] = -1e30f; }
    for (int j0 = 0; j0 < NTOK; j0 += 32) {
        __syncthreads();
        {
            float4 v0 = make_float4(0,0,0,0), v1 = v0;
            if (j0 + r < NTOK) {
                const float* kp = QKV + ((size_t)(b * NTOK + j0 + r)) * 1152 + 384 + hh * 64 + d0;
                v0 = *(const float4*)kp; v1 = *(const float4*)(kp + 4);
            }
            ks[r][d0+0]=v0.x; ks[r][d0+1]=v0.y; ks[r][d0+2]=v0.z; ks[r][d0+3]=v0.w;
            ks[r][d0+4]=v1.x; ks[r][d0+5]=v1.y; ks[r][d0+6]=v1.z; ks[r][d0+7]=v1.w;
        }
        __syncthreads();
        float acc[4] = {0.f, 0.f, 0.f, 0.f};
        #pragma unroll 8
        for (int d = 0; d < 64; ++d) {
            float qv = qs[r][d];
            #pragma unroll
            for (int u = 0; u < 4; ++u) acc[u] += qv * ks[c0 + u][d];
        }
        #pragma unroll
        for (int u = 0; u < 4; ++u) {
            int j = j0 + c0 + u;
            if (j < NTOK) srow[r][j] = acc[u] * 0.125f;
        }
    }
    __syncthreads();
    float m = -1e30f;
    for (int c = l8; c < 200; c += 8) m = fmaxf(m, srow[r][c]);
    #pragma unroll
    for (int off = 1; off < 8; off <<= 1) m = fmaxf(m, __shfl_xor(m, off));
    float s = 0.f;
    for (int c = l8; c < 200; c += 8) {
        float e = expf(srow[r][c] - m);
        srow[r][c] = e;
        s += e;
    }
    #pragma unroll
    for (int off = 1; off < 8; off <<= 1) s += __shfl_xor(s, off);
    float invs = 1.f / s;
    int i = i0 + r;
    if (i < NTOK) {
        float* sp = S + ((size_t)z * NTOK + i) * NTOK;
        for (int c = l8; c < NTOK; c += 8) sp[c] = srow[r][c] * invs;
    }
}

// ---------------- PV ----------------
__global__ __launch_bounds__(256) void k_pv(const float* __restrict__ S, const float* __restrict__ QKV,
                                            float* __restrict__ AO) {
    int z = blockIdx.y;
    int b = z / NHEAD, hh = z % NHEAD;
    int i0 = blockIdx.x * 32;
    __shared__ float ps[32][33];
    __shared__ float vs[32][65];
    int tid = threadIdx.x;
    int r = tid >> 3;
    int c4 = (tid & 7) * 4;
    int d0 = (tid & 7) * 8;
    float acc[8] = {};
    for (int k0 = 0; k0 < NTOK; k0 += 32) {
        #pragma unroll
        for (int u = 0; u < 4; ++u) {
            int i = i0 + r, j = k0 + c4 + u;
            ps[r][c4 + u] = (i < NTOK && j < NTOK) ? S[((size_t)z * NTOK + i) * NTOK + j] : 0.f;
        }
        {
            float4 v0 = make_float4(0,0,0,0), v1 = v0;
            if (k0 + r < NTOK) {
                const float* vp = QKV + ((size_t)(b * NTOK + k0 + r)) * 1152 + 768 + hh * 64 + d0;
                v0 = *(const float4*)vp; v1 = *(const float4*)(vp + 4);
            }
            vs[r][d0+0]=v0.x; vs[r][d0+1]=v0.y; vs[r][d0+2]=v0.z; vs[r][d0+3]=v0.w;
            vs[r][d0+4]=v1.x; vs[r][d0+5]=v1.y; vs[r][d0+6]=v1.z; vs[r][d0+7]=v1.w;
        }
        __syncthreads();
        #pragma unroll 8
        for (int kk = 0; kk < 32; ++kk) {
            float pw = ps[r][kk];
            #pragma unroll
            for (int j = 0; j < 8; ++j) acc[j] += pw * vs[kk][d0 + j];
        }
        __syncthreads();
    }
    int i = i0 + r;
    if (i < NTOK) {
        float* op = AO + (size_t)(b * NTOK + i) * DM + hh * 64 + d0;
        #pragma unroll
        for (int j = 0; j < 8; ++j) op[j] = acc[j];
    }
}

// ---------------- MoE routing: self-contained LN stats + gating ----------------
__global__ void k_route_ln(const float* __restrict__ H, float* __restrict__ lnstat,
                           const float* __restrict__ lnw, const float* __restrict__ lnb,
                           const float* __restrict__ GW,
                           int* __restrict__ eidx, float* __restrict__ egate) {
    int t = blockIdx.x * 4 + (threadIdx.x >> 6);
    if (t >= TT) return;
    int lane = threadIdx.x & 63;
    const float* x = H + (size_t)t * DM;
    float v[6];
    float s = 0.f, ss = 0.f;
    #pragma unroll
    for (int i = 0; i < 6; ++i) {
        v[i] = x[lane + i * 64];
        s += v[i];
        ss += v[i] * v[i];
    }
    #pragma unroll
    for (int off = 32; off; off >>= 1) { s += __shfl_xor(s, off); ss += __shfl_xor(ss, off); }
    float mean = s * (1.f / 384.f);
    float var = ss * (1.f / 384.f) - mean * mean;
    float inv = rsqrtf(var + 1e-6f);
    if (lane == 0) { lnstat[2 * t] = mean; lnstat[2 * t + 1] = inv; }
    float l8v[NEXP] = {};
    #pragma unroll
    for (int i = 0; i < 6; ++i) {
        int d = lane + i * 64;
        float yv = (v[i] - mean) * inv * lnw[d] + lnb[d];
        const float* g = GW + (size_t)d * NEXP;
        #pragma unroll
        for (int e = 0; e < NEXP; ++e) l8v[e] += yv * g[e];
    }
    #pragma unroll
    for (int e = 0; e < NEXP; ++e) {
        float vv = l8v[e];
        #pragma unroll
        for (int off = 32; off; off >>= 1) vv += __shfl_xor(vv, off);
        l8v[e] = vv;
    }
    if (lane == 0) {
        int b0 = 0;
        #pragma unroll
        for (int e = 1; e < NEXP; ++e) if (l8v[e] > l8v[b0]) b0 = e;
        int b1 = -1;
        #pragma unroll
        for (int e = 0; e < NEXP; ++e) if (e != b0 && (b1 < 0 || l8v[e] > l8v[b1])) b1 = e;
        float e1 = expf(l8v[b1] - l8v[b0]);
        float denom = 1.f + e1;
        eidx[2 * t] = b0; eidx[2 * t + 1] = b1;
        egate[2 * t] = 1.f / denom; egate[2 * t + 1] = e1 / denom;
    }
}

// ---------------- count + prefix + scatter, one block ----------------
__global__ void k_pscatter(int* __restrict__ cnt, int* __restrict__ basep,
                           const int* __restrict__ eidx,
                           int* __restrict__ slot_tok, int* __restrict__ slot_of) {
    __shared__ int hist[NEXP];
    __shared__ int bp[NEXP];
    __shared__ int fl[NEXP];
    int tid = threadIdx.x;
    if (tid < NEXP) { hist[tid] = 0; fl[tid] = 0; }
    __syncthreads();
    for (int i = tid; i < 2 * TT; i += 256) atomicAdd(&hist[eidx[i]], 1);
    __syncthreads();
    if (tid == 0) {
        int s = 0;
        for (int e = 0; e < NEXP; ++e) { bp[e] = s; s += hist[e]; }
    }
    __syncthreads();
    if (tid < NEXP) { cnt[tid] = hist[tid]; basep[tid] = bp[tid]; }
    for (int t = tid; t < TT; t += 256) {
        #pragma unroll
        for (int k = 0; k < 2; ++k) {
            int e = eidx[2 * t + k];
            int pos = atomicAdd(&fl[e], 1);
            int s = bp[e] + pos;
            slot_tok[s] = t;
            slot_of[2 * t + k] = s;
        }
    }
}

// =====================================================================
// MoE FFN1 (LN fused on A): flat grid 8*13*24; e = bid&7 pins expert->XCD.
// =====================================================================
__global__ __launch_bounds__(256) void k_moe1_mfma(
    const float* __restrict__ H, const float* __restrict__ lnstat,
    const float* __restrict__ lnw, const float* __restrict__ lnb,
    const float* __restrict__ W1, const float* __restrict__ B1,
    const int* __restrict__ slot_tok, const int* __restrict__ cnt, const int* __restrict__ basep,
    float* __restrict__ HID)
{
    const int e = blockIdx.x & 7;
    const int idx = blockIdx.x >> 3;
    const int mt = idx % 13;
    const int nt = idx / 13;
    const int c = cnt[e];
    const int r0 = mt * 64;
    if (r0 >= c) return;
    const int sbase = basep[e];
    const int n0 = nt * 64;
    const float* W = W1 + (size_t)e * DM * HM;
    const float* B1e = B1 + (size_t)e * HM;
    __shared__ short Ah[64 * LD2], Al[64 * LD2], Bh[64 * LD2], Bl[64 * LD2];
    const int tid = threadIdx.x;
    const int lane = tid & 63, w = tid >> 6;
    const int wr = w >> 1, wc = w & 1;
    const int r16 = lane & 15, g = lane >> 4;
    const int sr = tid >> 4, sc = (tid & 15) * 4;
    const int kq = (tid >> 4) * 4;
    int tokp[4];
    float am4[4], ai4[4];
    #pragma unroll
    for (int p = 0; p < 4; ++p) {
        int m = r0 + sr + p * 16;
        tokp[p] = (m < c) ? slot_tok[sbase + m] : -1;
        am4[p] = 0.f; ai4[p] = 1.f;
        if (tokp[p] >= 0) { am4[p] = lnstat[2 * tokp[p]]; ai4[p] = lnstat[2 * tokp[p] + 1]; }
    }
    f32x4 acc[2][2] = {};
    for (int k0 = 0; k0 < DM; k0 += 64) {
        float4 lw4 = *(const float4*)(lnw + k0 + sc);
        float4 lb4 = *(const float4*)(lnb + k0 + sc);
        #pragma unroll
        for (int p = 0; p < 4; ++p) {
            int r = sr + p * 16;
            float4 a4 = make_float4(0.f, 0.f, 0.f, 0.f);
            if (tokp[p] >= 0) {
                a4 = *(const float4*)(H + (size_t)tokp[p] * DM + k0 + sc);
                a4.x = (a4.x - am4[p]) * ai4[p] * lw4.x + lb4.x;
                a4.y = (a4.y - am4[p]) * ai4[p] * lw4.y + lb4.y;
                a4.z = (a4.z - am4[p]) * ai4[p] * lw4.z + lb4.z;
                a4.w = (a4.w - am4[p]) * ai4[p] * lw4.w + lb4.w;
            }
            short4 ah, al;
            f2bf2(a4.x, ah.x, al.x); f2bf2(a4.y, ah.y, al.y);
            f2bf2(a4.z, ah.z, al.z); f2bf2(a4.w, ah.w, al.w);
            *(short4*)&Ah[r * LD2 + sc] = ah; *(short4*)&Al[r * LD2 + sc] = al;
        }
        {
            float4 b4[4];
            #pragma unroll
            for (int i = 0; i < 4; ++i)
                b4[i] = *(const float4*)(W + (size_t)(k0 + kq + i) * HM + n0 + sc);
            float col[4][4] = {
                { b4[0].x, b4[1].x, b4[2].x, b4[3].x },
                { b4[0].y, b4[1].y, b4[2].y, b4[3].y },
                { b4[0].z, b4[1].z, b4[2].z, b4[3].z },
                { b4[0].w, b4[1].w, b4[2].w, b4[3].w } };
            #pragma unroll
            for (int u = 0; u < 4; ++u) {
                short4 hh, ll;
                f2bf2(col[u][0], hh.x, ll.x); f2bf2(col[u][1], hh.y, ll.y);
                f2bf2(col[u][2], hh.z, ll.z); f2bf2(col[u][3], hh.w, ll.w);
                *(short4*)&Bh[(sc + u) * LD2 + kq] = hh;
                *(short4*)&Bl[(sc + u) * LD2 + kq] = ll;
            }
        }
        __syncthreads();
        #pragma unroll
        for (int kk = 0; kk < 2; ++kk) {
            bf16x8 afh[2], afl[2], bfh[2], bfl[2];
            #pragma unroll
            for (int i = 0; i < 2; ++i) {
                int off = (wr * 32 + i * 16 + r16) * LD2 + kk * 32 + g * 8;
                afh[i] = *(const bf16x8*)&Ah[off];
                afl[i] = *(const bf16x8*)&Al[off];
            }
            #pragma unroll
            for (int j = 0; j < 2; ++j) {
                int off = (wc * 32 + j * 16 + r16) * LD2 + kk * 32 + g * 8;
                bfh[j] = *(const bf16x8*)&Bh[off];
                bfl[j] = *(const bf16x8*)&Bl[off];
            }
            #pragma unroll
            for (int i = 0; i < 2; ++i)
                #pragma unroll
                for (int j = 0; j < 2; ++j) {
                    acc[i][j] = __builtin_amdgcn_mfma_f32_16x16x32_bf16(afl[i], bfh[j], acc[i][j], 0, 0, 0);
                    acc[i][j] = __builtin_amdgcn_mfma_f32_16x16x32_bf16(afh[i], bfl[j], acc[i][j], 0, 0, 0);
                    acc[i][j] = __builtin_amdgcn_mfma_f32_16x16x32_bf16(afh[i], bfh[j], acc[i][j], 0, 0, 0);
                }
        }
        __syncthreads();
    }
    #pragma unroll
    for (int i = 0; i < 2; ++i) {
        #pragma unroll
        for (int j = 0; j < 2; ++j) {
            int n = n0 + wc * 32 + j * 16 + r16;
            float bb = B1e[n];
            #pragma unroll
            for (int r = 0; r < 4; ++r) {
                int m = r0 + wr * 32 + i * 16 + g * 4 + r;
                if (m < c)
                    HID[(size_t)(sbase + m) * HM + n] = gelu_f(acc[i][j][r] + bb);
            }
        }
    }
}

// =====================================================================
// MoE FFN2: flat grid 8*13*24; e = bid&7; K-split 4 -> partials.
// =====================================================================
__global__ __launch_bounds__(256) void k_moe2_mfma(
    const float* __restrict__ HID, const float* __restrict__ W2,
    const int* __restrict__ cnt, const int* __restrict__ basep,
    float* __restrict__ MOUTP)
{
    const int e = blockIdx.x & 7;
    const int idx = blockIdx.x >> 3;
    const int mt = idx % 13;
    const int rest = idx / 13;
    const int nt = rest % 6;
    const int ks = rest / 6;
    const int c = cnt[e];
    const int r0 = mt * 64;
    if (r0 >= c) return;
    const int sbase = basep[e];
    const int n0 = nt * 64;
    const int kbase = ks * 384;
    const float* W = W2 + (size_t)e * HM * DM + (size_t)kbase * DM;
    float* outp = MOUTP + (size_t)ks * MOUTSZ;
    __shared__ short Ah[64 * LD2], Al[64 * LD2], Bh[64 * LD2], Bl[64 * LD2];
    const int tid = threadIdx.x;
    const int lane = tid & 63, w = tid >> 6;
    const int wr = w >> 1, wc = w & 1;
    const int r16 = lane & 15, g = lane >> 4;
    const int sr = tid >> 4, sc = (tid & 15) * 4;
    const int kq = (tid >> 4) * 4;
    f32x4 acc[2][2] = {};
    for (int k0 = 0; k0 < 384; k0 += 64) {
        #pragma unroll
        for (int p = 0; p < 4; ++p) {
            int r = sr + p * 16;
            int m = r0 + r;
            float4 a4 = make_float4(0.f, 0.f, 0.f, 0.f);
            if (m < c) a4 = *(const float4*)(HID + (size_t)(sbase + m) * HM + kbase + k0 + sc);
            short4 ah, al;
            f2bf2(a4.x, ah.x, al.x); f2bf2(a4.y, ah.y, al.y);
            f2bf2(a4.z, ah.z, al.z); f2bf2(a4.w, ah.w, al.w);
            *(short4*)&Ah[r * LD2 + sc] = ah; *(short4*)&Al[r * LD2 + sc] = al;
        }
        {
            float4 b4[4];
            #pragma unroll
            for (int i = 0; i < 4; ++i)
                b4[i] = *(const float4*)(W + (size_t)(k0 + kq + i) * DM + n0 + sc);
            float col[4][4] = {
                { b4[0].x, b4[1].x, b4[2].x, b4[3].x },
                { b4[0].y, b4[1].y, b4[2].y, b4[3].y },
                { b4[0].z, b4[1].z, b4[2].z, b4[3].z },
                { b4[0].w, b4[1].w, b4[2].w, b4[3].w } };
            #pragma unroll
            for (int u = 0; u < 4; ++u) {
                short4 hh, ll;
                f2bf2(col[u][0], hh.x, ll.x); f2bf2(col[u][1], hh.y, ll.y);
                f2bf2(col[u][2], hh.z, ll.z); f2bf2(col[u][3], hh.w, ll.w);
                *(short4*)&Bh[(sc + u) * LD2 + kq] = hh;
                *(short4*)&Bl[(sc + u) * LD2 + kq] = ll;
            }
        }
        __syncthreads();
        #pragma unroll
        for (int kk = 0; kk < 2; ++kk) {
            bf16x8 afh[2], afl[2], bfh[2], bfl[2];
            #pragma unroll
            for (int i = 0; i < 2; ++i) {
                int off = (wr * 32 + i * 16 + r16) * LD2 + kk * 32 + g * 8;
                afh[i] = *(const bf16x8*)&Ah[off];
                afl[i] = *(const bf16x8*)&Al[off];
            }
            #pragma unroll
            for (int j = 0; j < 2; ++j) {
                int off = (wc * 32 + j * 16 + r16) * LD2 + kk * 32 + g * 8;
                bfh[j] = *(const bf16x8*)&Bh[off];
                bfl[j] = *(const bf16x8*)&Bl[off];
            }
            #pragma unroll
            for (int i = 0; i < 2; ++i)
                #pragma unroll
                for (int j = 0; j < 2; ++j) {
                    acc[i][j] = __builtin_amdgcn_mfma_f32_16x16x32_bf16(afl[i], bfh[j], acc[i][j], 0, 0, 0);
                    acc[i][j] = __builtin_amdgcn_mfma_f32_16x16x32_bf16(afh[i], bfl[j], acc[i][j], 0, 0, 0);
                    acc[i][j] = __builtin_amdgcn_mfma_f32_16x16x32_bf16(afh[i], bfh[j], acc[i][j], 0, 0, 0);
                }
        }
        __syncthreads();
    }
    #pragma unroll
    for (int i = 0; i < 2; ++i) {
        #pragma unroll
        for (int j = 0; j < 2; ++j) {
            int n = n0 + wc * 32 + j * 16 + r16;
            #pragma unroll
            for (int r = 0; r < 4; ++r) {
                int m = r0 + wr * 32 + i * 16 + g * 4 + r;
                if (m < c)
                    outp[(size_t)(sbase + m) * DM + n] = acc[i][j][r];
            }
        }
    }
}

// ---------------- combine ----------------
__global__ void k_combine(const float* __restrict__ MOUTP, const int* __restrict__ slot_of,
                          const int* __restrict__ eidx, const float* __restrict__ egate,
                          const float* __restrict__ B2, float* __restrict__ H) {
    int t = blockIdx.x;
    int s0 = slot_of[2 * t], s1 = slot_of[2 * t + 1];
    int e0 = eidx[2 * t], e1 = eidx[2 * t + 1];
    float g0 = egate[2 * t], g1 = egate[2 * t + 1];
    for (int d = threadIdx.x; d < DM; d += 128) {
        float v0 = B2[(size_t)e0 * DM + d];
        float v1 = B2[(size_t)e1 * DM + d];
        #pragma unroll
        for (int p = 0; p < 4; ++p) {
            v0 += MOUTP[(size_t)p * MOUTSZ + (size_t)s0 * DM + d];
            v1 += MOUTP[(size_t)p * MOUTSZ + (size_t)s1 * DM + d];
        }
        H[(size_t)t * DM + d] += g0 * v0 + g1 * v1;
    }
}

extern "C" void kernel_launch(void* const* d_in, const int* in_sizes, int n_in,
                              void* d_out, int out_size, void* d_ws, size_t ws_size,
                              hipStream_t stream) {
    const float* x         = (const float*)d_in[0];
    const float* patch_w   = (const float*)d_in[1];
    const float* patch_b   = (const float*)d_in[2];
    const float* cls_token = (const float*)d_in[3];
    const float* pos_embed = (const float*)d_in[4];
    const float* ln1_w     = (const float*)d_in[5];
    const float* ln1_b     = (const float*)d_in[6];
    const float* qkv_w     = (const float*)d_in[7];
    const float* qkv_b     = (const float*)d_in[8];
    const float* proj_w    = (const float*)d_in[9];
    const float* proj_b    = (const float*)d_in[10];
    const float* ln2_w     = (const float*)d_in[11];
    const float* ln2_b     = (const float*)d_in[12];
    const float* fc1_w     = (const float*)d_in[13];
    const float* fc1_b     = (const float*)d_in[14];
    const float* fc2_w     = (const float*)d_in[15];
    const float* fc2_b     = (const float*)d_in[16];
    const float* gate_w    = (const float*)d_in[17];
    const float* moe_w1    = (const float*)d_in[18];
    const float* moe_b1    = (const float*)d_in[19];
    const float* moe_w2    = (const float*)d_in[20];
    const float* moe_b2    = (const float*)d_in[21];
    const float* lnf_w     = (const float*)d_in[22];
    const float* lnf_b     = (const float*)d_in[23];
    float* out = (float*)d_out;

    float* wsf = (float*)d_ws;
    float* regA     = wsf;
    float* patches  = regA;                 // 784*768
    float* patchout = regA + 602112;        // 784*384
    float* moehid   = regA;                 // 1576*1536 = 2420736
    float* h     = regA + 2420736;          // 788*384
    float* spare = h + 302592;              // layout stability
    float* qkvb  = spare + 302592;          // 788*1152
    float* attno = qkvb + 907776;           // 788*384
    float* regC  = attno + 302592;          // S / dense-hid (1210368 floats)
    float* S    = regC;
    float* hid  = regC;
    float* mout4 = qkvb;                    // 4*605184 spans qkvb..end(regC)
    float* egate = regC + 1210368;
    int* ib       = (int*)(egate + 1576);
    int* eidx     = ib;
    int* slot_tok = ib + 1576;
    int* slot_of  = ib + 3152;
    int* cnt      = ib + 4728;
    int* basep    = ib + 4736;
    float* lnstat = (float*)(ib + 4752);    // TT*2 floats

    // ---- patch embed ----
    k_im2col<<<784, 256, 0, stream>>>(x, patches);
    k_gemm_mfma<<<96, 256, 0, stream>>>(patches, patch_w, nullptr, patchout,
                                        784, DM, 768, 0, 13, 6, 0, 1, nullptr, nullptr);
    k_assemble<<<TT, 128, 0, stream>>>(patchout, patch_b, cls_token, pos_embed, h);

    for (int l = 0; l < 12; ++l) {
        // attention (LN stats computed inside the GEMM)
        k_gemm_mfma<<<312, 256, 0, stream>>>(h, qkv_w + (size_t)l * 1152 * DM,
                                             qkv_b + l * 1152, qkvb, TT, 1152, DM, 8,
                                             13, 18, 1, 1,
                                             ln1_w + l * DM, ln1_b + l * DM);
        k_scoresm<<<dim3(7, NBATCH * NHEAD), 256, 0, stream>>>(qkvb, S);
        k_pv<<<dim3(7, NBATCH * NHEAD), 256, 0, stream>>>(S, qkvb, attno);
        // proj: K-split 2, atomic accumulate into h. grid 8*2*6*2 = 192
        k_gemm_mfma<<<192, 256, 0, stream>>>(attno, proj_w + (size_t)l * DM * DM,
                                             proj_b + l * DM, h, TT, DM, DM, 16,
                                             13, 6, 0, 2, nullptr, nullptr);
        // ffn
        int j = l >> 1;
        if ((l & 1) == 0) {
            k_gemm_mfma<<<312, 256, 0, stream>>>(h, fc1_w + (size_t)j * HM * DM,
                                                 fc1_b + j * HM, hid, TT, HM, DM, 9,
                                                 13, 24, 1, 1,
                                                 ln2_w + l * DM, ln2_b + l * DM);
            // fc2: K-split 4, atomic accumulate into h. grid 8*4*6*2 = 384
            k_gemm_mfma<<<384, 256, 0, stream>>>(hid, fc2_w + (size_t)j * DM * HM,
                                                 fc2_b + j * DM, h, TT, DM, HM, 16,
                                                 13, 6, 0, 4, nullptr, nullptr);
        } else {
            k_route_ln<<<197, 256, 0, stream>>>(h, lnstat, ln2_w + l * DM, ln2_b + l * DM,
                                                gate_w + (size_t)j * DM * NEXP, eidx, egate);
            k_pscatter<<<1, 256, 0, stream>>>(cnt, basep, eidx, slot_tok, slot_of);
            k_moe1_mfma<<<8 * 13 * 24, 256, 0, stream>>>(
                h, lnstat, ln2_w + l * DM, ln2_b + l * DM,
                moe_w1 + (size_t)j * NEXP * DM * HM, moe_b1 + (size_t)j * NEXP * HM,
                slot_tok, cnt, basep, moehid);
            k_moe2_mfma<<<8 * 13 * 24, 256, 0, stream>>>(
                moehid, moe_w2 + (size_t)j * NEXP * HM * DM, cnt, basep, mout4);
            k_combine<<<TT, 128, 0, stream>>>(mout4, slot_of, eidx, egate,
                                              moe_b2 + (size_t)j * NEXP * DM, h);
        }
    }
    k_ln<<<TT, 64, 0, stream>>>(h, lnf_w, lnf_b, out);
}

// Round 19
// 1630.103 us; speedup vs baseline: 2.8114x; 1.0242x over previous
//
#include <hip/hip_runtime.h>
#include <math.h>

#define NBATCH 4
#define NTOK 197
#define TT 788            // NBATCH*NTOK
#define DM 384
#define HM 1536
#define NHEAD 6
#define NEXP 8
#define LD2 72            // LDS row stride (shorts) for 64-k tiles (+8 pad)
#define MOUTSZ (TT * 2 * DM)

typedef __attribute__((ext_vector_type(8))) short bf16x8;
typedef __attribute__((ext_vector_type(4))) float f32x4;

__device__ __forceinline__ void f2bf2(float x, short& hi, short& lo) {
    unsigned u = __float_as_uint(x);
    unsigned uh = u + (0x7fffu + ((u >> 16) & 1u));
    hi = (short)(uh >> 16);
    float hf = __uint_as_float(uh & 0xffff0000u);
    float r = x - hf;
    unsigned v = __float_as_uint(r);
    lo = (short)((v + (0x7fffu + ((v >> 16) & 1u))) >> 16);
}
__device__ __forceinline__ float gelu_f(float x) {
    return 0.5f * x * (1.0f + erff(x * 0.7071067811865475f));
}

// ---------------- im2col ----------------
__global__ void k_im2col(const float* __restrict__ X, float* __restrict__ P) {
    int p = blockIdx.x;
    int b = p / 196, pp = p % 196;
    int py = pp / 14, px = pp % 14;
    const float* xb = X + (size_t)b * 3 * 224 * 224;
    float* dst = P + (size_t)p * 768;
    for (int idx = threadIdx.x; idx < 768; idx += 256) {
        int c = idx >> 8;
        int i = (idx >> 4) & 15;
        int j = idx & 15;
        dst[idx] = xb[((size_t)c * 224 + py * 16 + i) * 224 + px * 16 + j];
    }
}

// ---------------- assemble tokens ----------------
__global__ void k_assemble(const float* __restrict__ PO, const float* __restrict__ pb,
                           const float* __restrict__ cls, const float* __restrict__ pos,
                           float* __restrict__ H) {
    int t = blockIdx.x;
    int b = t / NTOK, n = t % NTOK;
    for (int d = threadIdx.x; d < DM; d += 128) {
        float v;
        if (n == 0) v = cls[d];
        else v = PO[((size_t)b * 196 + (n - 1)) * DM + d] + pb[d];
        H[(size_t)t * DM + d] = v + pos[(size_t)n * DM + d];
    }
}

// ---------------- layernorm (final output only) ----------------
__global__ void k_ln(const float* __restrict__ X, const float* __restrict__ w,
                     const float* __restrict__ b, float* __restrict__ Y) {
    int t = blockIdx.x, lane = threadIdx.x;
    const float* x = X + (size_t)t * DM;
    float v[6];
    float s = 0.f;
    #pragma unroll
    for (int i = 0; i < 6; ++i) { v[i] = x[lane + i * 64]; s += v[i]; }
    #pragma unroll
    for (int off = 32; off; off >>= 1) s += __shfl_xor(s, off);
    float mean = s * (1.f / 384.f);
    float q = 0.f;
    #pragma unroll
    for (int i = 0; i < 6; ++i) { float d = v[i] - mean; q += d * d; }
    #pragma unroll
    for (int off = 32; off; off >>= 1) q += __shfl_xor(q, off);
    float inv = rsqrtf(q * (1.f / 384.f) + 1e-6f);
    float* y = Y + (size_t)t * DM;
    #pragma unroll
    for (int i = 0; i < 6; ++i) {
        int d = lane + i * 64;
        y[d] = (v[i] - mean) * inv * w[d] + b[d];
    }
}

// =====================================================================
// Pipelined split-precision MFMA GEMM: C = A@W^T, BK=64. (64x64 tile)
// flags: 1=gelu-out, 2=accumulate, 8=LN-on-A (stats in-block; K==384),
//        16=atomicAdd output (K-split partials; bias added by ks==0 only).
// =====================================================================
__global__ __launch_bounds__(256) void k_gemm_mfma(
    const float* __restrict__ A, const float* __restrict__ W,
    const float* __restrict__ bias, float* __restrict__ C,
    int M, int N, int K, int flags, int MT, int NT, int wprot, int ksplit,
    const float* __restrict__ lnw, const float* __restrict__ lnb)
{
    int mt, nt, ks = 0;
    {
        int lane8 = blockIdx.x & 7;
        int idx = blockIdx.x >> 3;
        if (ksplit > 1) { ks = idx % ksplit; idx /= ksplit; }
        if (wprot) {
            mt = idx % MT;
            nt = lane8 + 8 * (idx / MT);
            if (nt >= NT) return;
        } else {
            nt = idx % NT;
            mt = lane8 + 8 * (idx / NT);
            if (mt >= MT) return;
        }
    }
    const int Ks = K / ksplit;
    const float* Ab = A + (size_t)ks * Ks;
    const float* Wb = W + (size_t)ks * Ks;
    __shared__ short Ah[64 * LD2], Al[64 * LD2], Bh[64 * LD2], Bl[64 * LD2];
    const int bm = mt * 64, bn = nt * 64;
    const int tid = threadIdx.x;
    const int lane = tid & 63, w = tid >> 6;
    const int wr = w >> 1, wc = w & 1;
    const int r16 = lane & 15, g = lane >> 4;
    const int sr = tid >> 4;          // 0..15
    const int sc = (tid & 15) * 4;    // 0..60
    const bool doln = (flags & 8) != 0;
    float am[4], ai[4];
    #pragma unroll
    for (int p = 0; p < 4; ++p) { am[p] = 0.f; ai[p] = 1.f; }
    if (doln) {
        int j = tid & 15;
        #pragma unroll
        for (int p = 0; p < 4; ++p) {
            int r = bm + sr + p * 16;
            if (r < M) {
                const float* xr = A + (size_t)r * K;
                float s = 0.f, ss = 0.f;
                #pragma unroll
                for (int i = 0; i < 6; ++i) {
                    float4 v = *(const float4*)(xr + j * 4 + i * 64);
                    s += v.x + v.y + v.z + v.w;
                    ss += v.x * v.x + v.y * v.y + v.z * v.z + v.w * v.w;
                }
                #pragma unroll
                for (int off = 1; off < 16; off <<= 1) {
                    s += __shfl_xor(s, off);
                    ss += __shfl_xor(ss, off);
                }
                float mean = s * (1.f / 384.f);
                float var = ss * (1.f / 384.f) - mean * mean;
                am[p] = mean;
                ai[p] = rsqrtf(var + 1e-6f);
            }
        }
    }
    float4 ra[4], rb[4], lw4, lb4;
    auto LOADT = [&](int k0) {
        if (doln) {
            lw4 = *(const float4*)(lnw + k0 + sc);
            lb4 = *(const float4*)(lnb + k0 + sc);
        }
        #pragma unroll
        for (int p = 0; p < 4; ++p) {
            int r = sr + p * 16;
            ra[p] = make_float4(0.f, 0.f, 0.f, 0.f);
            if (bm + r < M) ra[p] = *(const float4*)(Ab + (size_t)(bm + r) * K + k0 + sc);
            rb[p] = *(const float4*)(Wb + (size_t)(bn + r) * K + k0 + sc);
        }
    };
    auto STORET = [&]() {
        #pragma unroll
        for (int p = 0; p < 4; ++p) {
            int r = sr + p * 16;
            float4 a4 = ra[p];
            if (doln) {
                a4.x = (a4.x - am[p]) * ai[p] * lw4.x + lb4.x;
                a4.y = (a4.y - am[p]) * ai[p] * lw4.y + lb4.y;
                a4.z = (a4.z - am[p]) * ai[p] * lw4.z + lb4.z;
                a4.w = (a4.w - am[p]) * ai[p] * lw4.w + lb4.w;
            }
            float4 b4 = rb[p];
            short4 ah, al, bh, bl;
            f2bf2(a4.x, ah.x, al.x); f2bf2(a4.y, ah.y, al.y);
            f2bf2(a4.z, ah.z, al.z); f2bf2(a4.w, ah.w, al.w);
            f2bf2(b4.x, bh.x, bl.x); f2bf2(b4.y, bh.y, bl.y);
            f2bf2(b4.z, bh.z, bl.z); f2bf2(b4.w, bh.w, bl.w);
            *(short4*)&Ah[r * LD2 + sc] = ah; *(short4*)&Al[r * LD2 + sc] = al;
            *(short4*)&Bh[r * LD2 + sc] = bh; *(short4*)&Bl[r * LD2 + sc] = bl;
        }
    };
    f32x4 acc[2][2] = {};
    auto COMPUTE = [&]() {
        #pragma unroll
        for (int kk = 0; kk < 2; ++kk) {
            bf16x8 afh[2], afl[2], bfh[2], bfl[2];
            #pragma unroll
            for (int i = 0; i < 2; ++i) {
                int off = (wr * 32 + i * 16 + r16) * LD2 + kk * 32 + g * 8;
                afh[i] = *(const bf16x8*)&Ah[off];
                afl[i] = *(const bf16x8*)&Al[off];
            }
            #pragma unroll
            for (int j = 0; j < 2; ++j) {
                int off = (wc * 32 + j * 16 + r16) * LD2 + kk * 32 + g * 8;
                bfh[j] = *(const bf16x8*)&Bh[off];
                bfl[j] = *(const bf16x8*)&Bl[off];
            }
            #pragma unroll
            for (int i = 0; i < 2; ++i)
                #pragma unroll
                for (int j = 0; j < 2; ++j) {
                    acc[i][j] = __builtin_amdgcn_mfma_f32_16x16x32_bf16(afl[i], bfh[j], acc[i][j], 0, 0, 0);
                    acc[i][j] = __builtin_amdgcn_mfma_f32_16x16x32_bf16(afh[i], bfl[j], acc[i][j], 0, 0, 0);
                    acc[i][j] = __builtin_amdgcn_mfma_f32_16x16x32_bf16(afh[i], bfh[j], acc[i][j], 0, 0, 0);
                }
        }
    };
    LOADT(0);
    STORET();
    __syncthreads();
    for (int k0 = 64; k0 < Ks; k0 += 64) {
        LOADT(k0);        // global loads in flight during compute
        COMPUTE();
        __syncthreads();  // all LDS reads done
        STORET();
        __syncthreads();
    }
    COMPUTE();
    #pragma unroll
    for (int i = 0; i < 2; ++i) {
        #pragma unroll
        for (int j = 0; j < 2; ++j) {
            int n = bn + wc * 32 + j * 16 + r16;
            float bb = (bias && ks == 0) ? bias[n] : 0.f;
            int mbase = bm + wr * 32 + i * 16 + g * 4;
            #pragma unroll
            for (int r = 0; r < 4; ++r) {
                int m = mbase + r;
                if (m < M) {
                    float v = acc[i][j][r] + bb;
                    float* cp = C + (size_t)m * N + n;
                    if (flags & 16) {
                        atomicAdd(cp, v);
                    } else {
                        if (flags & 1) v = gelu_f(v);
                        if (flags & 2) v += *cp;
                        *cp = v;
                    }
                }
            }
        }
    }
}

// =====================================================================
// 32-row-tile MFMA GEMM (more blocks, latency-bound shapes): C = A@W^T.
// Tile 32(M) x 64(N), BK=64, 4 waves each owning a 16-col strip.
// flags: 1=gelu-out, 8=LN-on-A (K must be 384). W-protect grid, no ksplit.
// Grid: 8 * MT25 * ceil(NT/8).
// =====================================================================
__global__ __launch_bounds__(256) void k_gemm32(
    const float* __restrict__ A, const float* __restrict__ W,
    const float* __restrict__ bias, float* __restrict__ C,
    int M, int N, int K, int flags, int MT, int NT,
    const float* __restrict__ lnw, const float* __restrict__ lnb)
{
    int mt, nt;
    {
        int lane8 = blockIdx.x & 7;
        int idx = blockIdx.x >> 3;
        mt = idx % MT;
        nt = lane8 + 8 * (idx / MT);
        if (nt >= NT) return;
    }
    __shared__ short Ah[32 * LD2], Al[32 * LD2], Bh[64 * LD2], Bl[64 * LD2];
    const int bm = mt * 32, bn = nt * 64;
    const int tid = threadIdx.x;
    const int lane = tid & 63, w = tid >> 6;     // wave 0..3: col strip w*16
    const int r16 = lane & 15, g = lane >> 4;
    // A staging: row sa = tid>>3 (0..31), 8 floats at k = (tid&7)*8
    const int sa = tid >> 3;
    const int ja = tid & 7;
    const int sca = ja * 8;
    // B staging: row sb = tid>>4 (+p*16), float4 at (tid&15)*4 (as 64-tile kernel)
    const int sr = tid >> 4;
    const int sc = (tid & 15) * 4;
    const bool doln = (flags & 8) != 0;
    const bool dogelu = (flags & 1) != 0;
    const int rowA = bm + sa;
    const bool aok = rowA < M;
    float am = 0.f, ai = 1.f;
    if (doln && aok) {
        // 8-thread row group; lanes ja contiguous within wave -> shfl ok
        const float* xr = A + (size_t)rowA * K;
        float s = 0.f, ss = 0.f;
        #pragma unroll
        for (int i = 0; i < 12; ++i) {
            float4 v = *(const float4*)(xr + ja * 48 + i * 4);
            s += v.x + v.y + v.z + v.w;
            ss += v.x * v.x + v.y * v.y + v.z * v.z + v.w * v.w;
        }
        #pragma unroll
        for (int off = 1; off < 8; off <<= 1) {
            s += __shfl_xor(s, off);
            ss += __shfl_xor(ss, off);
        }
        float mean = s * (1.f / 384.f);
        float var = ss * (1.f / 384.f) - mean * mean;
        am = mean;
        ai = rsqrtf(var + 1e-6f);
    }
    float4 ra0, ra1, rb[4], lwa0, lwa1, lba0, lba1;
    auto LOADT = [&](int k0) {
        if (doln) {
            lwa0 = *(const float4*)(lnw + k0 + sca);
            lwa1 = *(const float4*)(lnw + k0 + sca + 4);
            lba0 = *(const float4*)(lnb + k0 + sca);
            lba1 = *(const float4*)(lnb + k0 + sca + 4);
        }
        ra0 = make_float4(0.f, 0.f, 0.f, 0.f);
        ra1 = ra0;
        if (aok) {
            ra0 = *(const float4*)(A + (size_t)rowA * K + k0 + sca);
            ra1 = *(const float4*)(A + (size_t)rowA * K + k0 + sca + 4);
        }
        #pragma unroll
        for (int p = 0; p < 4; ++p) {
            int r = sr + p * 16;
            rb[p] = *(const float4*)(W + (size_t)(bn + r) * K + k0 + sc);
        }
    };
    auto STORET = [&]() {
        float4 a0 = ra0, a1 = ra1;
        if (doln) {
            a0.x = (a0.x - am) * ai * lwa0.x + lba0.x;
            a0.y = (a0.y - am) * ai * lwa0.y + lba0.y;
            a0.z = (a0.z - am) * ai * lwa0.z + lba0.z;
            a0.w = (a0.w - am) * ai * lwa0.w + lba0.w;
            a1.x = (a1.x - am) * ai * lwa1.x + lba1.x;
            a1.y = (a1.y - am) * ai * lwa1.y + lba1.y;
            a1.z = (a1.z - am) * ai * lwa1.z + lba1.z;
            a1.w = (a1.w - am) * ai * lwa1.w + lba1.w;
        }
        short4 h0, l0, h1, l1;
        f2bf2(a0.x, h0.x, l0.x); f2bf2(a0.y, h0.y, l0.y);
        f2bf2(a0.z, h0.z, l0.z); f2bf2(a0.w, h0.w, l0.w);
        f2bf2(a1.x, h1.x, l1.x); f2bf2(a1.y, h1.y, l1.y);
        f2bf2(a1.z, h1.z, l1.z); f2bf2(a1.w, h1.w, l1.w);
        *(short4*)&Ah[sa * LD2 + sca] = h0; *(short4*)&Ah[sa * LD2 + sca + 4] = h1;
        *(short4*)&Al[sa * LD2 + sca] = l0; *(short4*)&Al[sa * LD2 + sca + 4] = l1;
        #pragma unroll
        for (int p = 0; p < 4; ++p) {
            int r = sr + p * 16;
            float4 b4 = rb[p];
            short4 bh, bl;
            f2bf2(b4.x, bh.x, bl.x); f2bf2(b4.y, bh.y, bl.y);
            f2bf2(b4.z, bh.z, bl.z); f2bf2(b4.w, bh.w, bl.w);
            *(short4*)&Bh[r * LD2 + sc] = bh; *(short4*)&Bl[r * LD2 + sc] = bl;
        }
    };
    f32x4 acc[2] = {};
    auto COMPUTE = [&]() {
        #pragma unroll
        for (int kk = 0; kk < 2; ++kk) {
            bf16x8 afh[2], afl[2], bfh, bfl;
            #pragma unroll
            for (int i = 0; i < 2; ++i) {
                int off = (i * 16 + r16) * LD2 + kk * 32 + g * 8;
                afh[i] = *(const bf16x8*)&Ah[off];
                afl[i] = *(const bf16x8*)&Al[off];
            }
            {
                int off = (w * 16 + r16) * LD2 + kk * 32 + g * 8;
                bfh = *(const bf16x8*)&Bh[off];
                bfl = *(const bf16x8*)&Bl[off];
            }
            #pragma unroll
            for (int i = 0; i < 2; ++i) {
                acc[i] = __builtin_amdgcn_mfma_f32_16x16x32_bf16(afl[i], bfh, acc[i], 0, 0, 0);
                acc[i] = __builtin_amdgcn_mfma_f32_16x16x32_bf16(afh[i], bfl, acc[i], 0, 0, 0);
                acc[i] = __builtin_amdgcn_mfma_f32_16x16x32_bf16(afh[i], bfh, acc[i], 0, 0, 0);
            }
        }
    };
    LOADT(0);
    STORET();
    __syncthreads();
    for (int k0 = 64; k0 < K; k0 += 64) {
        LOADT(k0);
        COMPUTE();
        __syncthreads();
        STORET();
        __syncthreads();
    }
    COMPUTE();
    #pragma unroll
    for (int i = 0; i < 2; ++i) {
        int n = bn + w * 16 + r16;
        float bb = bias ? bias[n] : 0.f;
        int mbase = bm + i * 16 + g * 4;
        #pragma unroll
        for (int r = 0; r < 4; ++r) {
            int m = mbase + r;
            if (m < M) {
                float v = acc[i][r] + bb;
                if (dogelu) v = gelu_f(v);
                C[(size_t)m * N + n] = v;
            }
        }
    }
}

// =====================================================================
// Fused scores+softmax: writes normalized P into S. grid (7, 24).
// =====================================================================
__global__ __launch_bounds__(256) void k_scoresm(const float* __restrict__ QKV,
                                                 float* __restrict__ S) {
    int z = blockIdx.y;
    int b = z / NHEAD, hh = z % NHEAD;
    int i0 = blockIdx.x * 32;
    __shared__ float qs[32][65];
    __shared__ float ks[32][65];
    __shared__ float srow[32][200];
    int tid = threadIdx.x;
    int r = tid >> 3, d0 = (tid & 7) * 8, c0 = (tid & 7) * 4, l8 = tid & 7;
    {
        float4 v0 = make_float4(0,0,0,0), v1 = v0;
        if (i0 + r < NTOK) {
            const float* qp = QKV + ((size_t)(b * NTOK + i0 + r)) * 1152 + hh * 64 + d0;
            v0 = *(const float4*)qp; v1 = *(const float4*)(qp + 4);
        }
        qs[r][d0+0]=v0.x; qs[r][d0+1]=v0.y; qs[r][d0+2]=v0.z; qs[r][d0+3]=v0.w;
        qs[r][d0+4]=v1.x; qs[r][d0+5]=v1.y; qs[r][d0+6]=v1.z; qs[r][d0+7]=v1.w;
    }
    if (l8 == 0) { srow[r][197] = -1e30f; srow[r][198] = -1e30f; srow[r][199] = -1e30f; }
    for (int j0 = 0; j0 < NTOK; j0 += 32) {
        __syncthreads();
        {
            float4 v0 = make_float4(0,0,0,0), v1 = v0;
            if (j0 + r < NTOK) {
                const float* kp = QKV + ((size_t)(b * NTOK + j0 + r)) * 1152 + 384 + hh * 64 + d0;
                v0 = *(const float4*)kp; v1 = *(const float4*)(kp + 4);
            }
            ks[r][d0+0]=v0.x; ks[r][d0+1]=v0.y; ks[r][d0+2]=v0.z; ks[r][d0+3]=v0.w;
            ks[r][d0+4]=v1.x; ks[r][d0+5]=v1.y; ks[r][d0+6]=v1.z; ks[r][d0+7]=v1.w;
        }
        __syncthreads();
        float acc[4] = {0.f, 0.f, 0.f, 0.f};
        #pragma unroll 8
        for (int d = 0; d < 64; ++d) {
            float qv = qs[r][d];
            #pragma unroll
            for (int u = 0; u < 4; ++u) acc[u] += qv * ks[c0 + u][d];
        }
        #pragma unroll
        for (int u = 0; u < 4; ++u) {
            int j = j0 + c0 + u;
            if (j < NTOK) srow[r][j] = acc[u] * 0.125f;
        }
    }
    __syncthreads();
    float m = -1e30f;
    for (int c = l8; c < 200; c += 8) m = fmaxf(m, srow[r][c]);
    #pragma unroll
    for (int off = 1; off < 8; off <<= 1) m = fmaxf(m, __shfl_xor(m, off));
    float s = 0.f;
    for (int c = l8; c < 200; c += 8) {
        float e = expf(srow[r][c] - m);
        srow[r][c] = e;
        s += e;
    }
    #pragma unroll
    for (int off = 1; off < 8; off <<= 1) s += __shfl_xor(s, off);
    float invs = 1.f / s;
    int i = i0 + r;
    if (i < NTOK) {
        float* sp = S + ((size_t)z * NTOK + i) * NTOK;
        for (int c = l8; c < NTOK; c += 8) sp[c] = srow[r][c] * invs;
    }
}

// ---------------- PV ----------------
__global__ __launch_bounds__(256) void k_pv(const float* __restrict__ S, const float* __restrict__ QKV,
                                            float* __restrict__ AO) {
    int z = blockIdx.y;
    int b = z / NHEAD, hh = z % NHEAD;
    int i0 = blockIdx.x * 32;
    __shared__ float ps[32][33];
    __shared__ float vs[32][65];
    int tid = threadIdx.x;
    int r = tid >> 3;
    int c4 = (tid & 7) * 4;
    int d0 = (tid & 7) * 8;
    float acc[8] = {};
    for (int k0 = 0; k0 < NTOK; k0 += 32) {
        #pragma unroll
        for (int u = 0; u < 4; ++u) {
            int i = i0 + r, j = k0 + c4 + u;
            ps[r][c4 + u] = (i < NTOK && j < NTOK) ? S[((size_t)z * NTOK + i) * NTOK + j] : 0.f;
        }
        {
            float4 v0 = make_float4(0,0,0,0), v1 = v0;
            if (k0 + r < NTOK) {
                const float* vp = QKV + ((size_t)(b * NTOK + k0 + r)) * 1152 + 768 + hh * 64 + d0;
                v0 = *(const float4*)vp; v1 = *(const float4*)(vp + 4);
            }
            vs[r][d0+0]=v0.x; vs[r][d0+1]=v0.y; vs[r][d0+2]=v0.z; vs[r][d0+3]=v0.w;
            vs[r][d0+4]=v1.x; vs[r][d0+5]=v1.y; vs[r][d0+6]=v1.z; vs[r][d0+7]=v1.w;
        }
        __syncthreads();
        #pragma unroll 8
        for (int kk = 0; kk < 32; ++kk) {
            float pw = ps[r][kk];
            #pragma unroll
            for (int j = 0; j < 8; ++j) acc[j] += pw * vs[kk][d0 + j];
        }
        __syncthreads();
    }
    int i = i0 + r;
    if (i < NTOK) {
        float* op = AO + (size_t)(b * NTOK + i) * DM + hh * 64 + d0;
        #pragma unroll
        for (int j = 0; j < 8; ++j) op[j] = acc[j];
    }
}

// ---------------- MoE routing: self-contained LN stats + gating ----------------
__global__ void k_route_ln(const float* __restrict__ H, float* __restrict__ lnstat,
                           const float* __restrict__ lnw, const float* __restrict__ lnb,
                           const float* __restrict__ GW,
                           int* __restrict__ eidx, float* __restrict__ egate) {
    int t = blockIdx.x * 4 + (threadIdx.x >> 6);
    if (t >= TT) return;
    int lane = threadIdx.x & 63;
    const float* x = H + (size_t)t * DM;
    float v[6];
    float s = 0.f, ss = 0.f;
    #pragma unroll
    for (int i = 0; i < 6; ++i) {
        v[i] = x[lane + i * 64];
        s += v[i];
        ss += v[i] * v[i];
    }
    #pragma unroll
    for (int off = 32; off; off >>= 1) { s += __shfl_xor(s, off); ss += __shfl_xor(ss, off); }
    float mean = s * (1.f / 384.f);
    float var = ss * (1.f / 384.f) - mean * mean;
    float inv = rsqrtf(var + 1e-6f);
    if (lane == 0) { lnstat[2 * t] = mean; lnstat[2 * t + 1] = inv; }
    float l8v[NEXP] = {};
    #pragma unroll
    for (int i = 0; i < 6; ++i) {
        int d = lane + i * 64;
        float yv = (v[i] - mean) * inv * lnw[d] + lnb[d];
        const float* g = GW + (size_t)d * NEXP;
        #pragma unroll
        for (int e = 0; e < NEXP; ++e) l8v[e] += yv * g[e];
    }
    #pragma unroll
    for (int e = 0; e < NEXP; ++e) {
        float vv = l8v[e];
        #pragma unroll
        for (int off = 32; off; off >>= 1) vv += __shfl_xor(vv, off);
        l8v[e] = vv;
    }
    if (lane == 0) {
        int b0 = 0;
        #pragma unroll
        for (int e = 1; e < NEXP; ++e) if (l8v[e] > l8v[b0]) b0 = e;
        int b1 = -1;
        #pragma unroll
        for (int e = 0; e < NEXP; ++e) if (e != b0 && (b1 < 0 || l8v[e] > l8v[b1])) b1 = e;
        float e1 = expf(l8v[b1] - l8v[b0]);
        float denom = 1.f + e1;
        eidx[2 * t] = b0; eidx[2 * t + 1] = b1;
        egate[2 * t] = 1.f / denom; egate[2 * t + 1] = e1 / denom;
    }
}

// ---------------- count + prefix + scatter, one block ----------------
__global__ void k_pscatter(int* __restrict__ cnt, int* __restrict__ basep,
                           const int* __restrict__ eidx,
                           int* __restrict__ slot_tok, int* __restrict__ slot_of) {
    __shared__ int hist[NEXP];
    __shared__ int bp[NEXP];
    __shared__ int fl[NEXP];
    int tid = threadIdx.x;
    if (tid < NEXP) { hist[tid] = 0; fl[tid] = 0; }
    __syncthreads();
    for (int i = tid; i < 2 * TT; i += 256) atomicAdd(&hist[eidx[i]], 1);
    __syncthreads();
    if (tid == 0) {
        int s = 0;
        for (int e = 0; e < NEXP; ++e) { bp[e] = s; s += hist[e]; }
    }
    __syncthreads();
    if (tid < NEXP) { cnt[tid] = hist[tid]; basep[tid] = bp[tid]; }
    for (int t = tid; t < TT; t += 256) {
        #pragma unroll
        for (int k = 0; k < 2; ++k) {
            int e = eidx[2 * t + k];
            int pos = atomicAdd(&fl[e], 1);
            int s = bp[e] + pos;
            slot_tok[s] = t;
            slot_of[2 * t + k] = s;
        }
    }
}

// =====================================================================
// MoE FFN1 (LN fused on A): flat grid 8*13*24; e = bid&7 pins expert->XCD.
// =====================================================================
__global__ __launch_bounds__(256) void k_moe1_mfma(
    const float* __restrict__ H, const float* __restrict__ lnstat,
    const float* __restrict__ lnw, const float* __restrict__ lnb,
    const float* __restrict__ W1, const float* __restrict__ B1,
    const int* __restrict__ slot_tok, const int* __restrict__ cnt, const int* __restrict__ basep,
    float* __restrict__ HID)
{
    const int e = blockIdx.x & 7;
    const int idx = blockIdx.x >> 3;
    const int mt = idx % 13;
    const int nt = idx / 13;
    const int c = cnt[e];
    const int r0 = mt * 64;
    if (r0 >= c) return;
    const int sbase = basep[e];
    const int n0 = nt * 64;
    const float* W = W1 + (size_t)e * DM * HM;
    const float* B1e = B1 + (size_t)e * HM;
    __shared__ short Ah[64 * LD2], Al[64 * LD2], Bh[64 * LD2], Bl[64 * LD2];
    const int tid = threadIdx.x;
    const int lane = tid & 63, w = tid >> 6;
    const int wr = w >> 1, wc = w & 1;
    const int r16 = lane & 15, g = lane >> 4;
    const int sr = tid >> 4, sc = (tid & 15) * 4;
    const int kq = (tid >> 4) * 4;
    int tokp[4];
    float am4[4], ai4[4];
    #pragma unroll
    for (int p = 0; p < 4; ++p) {
        int m = r0 + sr + p * 16;
        tokp[p] = (m < c) ? slot_tok[sbase + m] : -1;
        am4[p] = 0.f; ai4[p] = 1.f;
        if (tokp[p] >= 0) { am4[p] = lnstat[2 * tokp[p]]; ai4[p] = lnstat[2 * tokp[p] + 1]; }
    }
    f32x4 acc[2][2] = {};
    for (int k0 = 0; k0 < DM; k0 += 64) {
        float4 lw4 = *(const float4*)(lnw + k0 + sc);
        float4 lb4 = *(const float4*)(lnb + k0 + sc);
        #pragma unroll
        for (int p = 0; p < 4; ++p) {
            int r = sr + p * 16;
            float4 a4 = make_float4(0.f, 0.f, 0.f, 0.f);
            if (tokp[p] >= 0) {
                a4 = *(const float4*)(H + (size_t)tokp[p] * DM + k0 + sc);
                a4.x = (a4.x - am4[p]) * ai4[p] * lw4.x + lb4.x;
                a4.y = (a4.y - am4[p]) * ai4[p] * lw4.y + lb4.y;
                a4.z = (a4.z - am4[p]) * ai4[p] * lw4.z + lb4.z;
                a4.w = (a4.w - am4[p]) * ai4[p] * lw4.w + lb4.w;
            }
            short4 ah, al;
            f2bf2(a4.x, ah.x, al.x); f2bf2(a4.y, ah.y, al.y);
            f2bf2(a4.z, ah.z, al.z); f2bf2(a4.w, ah.w, al.w);
            *(short4*)&Ah[r * LD2 + sc] = ah; *(short4*)&Al[r * LD2 + sc] = al;
        }
        {
            float4 b4[4];
            #pragma unroll
            for (int i = 0; i < 4; ++i)
                b4[i] = *(const float4*)(W + (size_t)(k0 + kq + i) * HM + n0 + sc);
            float col[4][4] = {
                { b4[0].x, b4[1].x, b4[2].x, b4[3].x },
                { b4[0].y, b4[1].y, b4[2].y, b4[3].y },
                { b4[0].z, b4[1].z, b4[2].z, b4[3].z },
                { b4[0].w, b4[1].w, b4[2].w, b4[3].w } };
            #pragma unroll
            for (int u = 0; u < 4; ++u) {
                short4 hh, ll;
                f2bf2(col[u][0], hh.x, ll.x); f2bf2(col[u][1], hh.y, ll.y);
                f2bf2(col[u][2], hh.z, ll.z); f2bf2(col[u][3], hh.w, ll.w);
                *(short4*)&Bh[(sc + u) * LD2 + kq] = hh;
                *(short4*)&Bl[(sc + u) * LD2 + kq] = ll;
            }
        }
        __syncthreads();
        #pragma unroll
        for (int kk = 0; kk < 2; ++kk) {
            bf16x8 afh[2], afl[2], bfh[2], bfl[2];
            #pragma unroll
            for (int i = 0; i < 2; ++i) {
                int off = (wr * 32 + i * 16 + r16) * LD2 + kk * 32 + g * 8;
                afh[i] = *(const bf16x8*)&Ah[off];
                afl[i] = *(const bf16x8*)&Al[off];
            }
            #pragma unroll
            for (int j = 0; j < 2; ++j) {
                int off = (wc * 32 + j * 16 + r16) * LD2 + kk * 32 + g * 8;
                bfh[j] = *(const bf16x8*)&Bh[off];
                bfl[j] = *(const bf16x8*)&Bl[off];
            }
            #pragma unroll
            for (int i = 0; i < 2; ++i)
                #pragma unroll
                for (int j = 0; j < 2; ++j) {
                    acc[i][j] = __builtin_amdgcn_mfma_f32_16x16x32_bf16(afl[i], bfh[j], acc[i][j], 0, 0, 0);
                    acc[i][j] = __builtin_amdgcn_mfma_f32_16x16x32_bf16(afh[i], bfl[j], acc[i][j], 0, 0, 0);
                    acc[i][j] = __builtin_amdgcn_mfma_f32_16x16x32_bf16(afh[i], bfh[j], acc[i][j], 0, 0, 0);
                }
        }
        __syncthreads();
    }
    #pragma unroll
    for (int i = 0; i < 2; ++i) {
        #pragma unroll
        for (int j = 0; j < 2; ++j) {
            int n = n0 + wc * 32 + j * 16 + r16;
            float bb = B1e[n];
            #pragma unroll
            for (int r = 0; r < 4; ++r) {
                int m = r0 + wr * 32 + i * 16 + g * 4 + r;
                if (m < c)
                    HID[(size_t)(sbase + m) * HM + n] = gelu_f(acc[i][j][r] + bb);
            }
        }
    }
}

// =====================================================================
// MoE FFN2: flat grid 8*13*24; e = bid&7; K-split 4 -> partials.
// =====================================================================
__global__ __launch_bounds__(256) void k_moe2_mfma(
    const float* __restrict__ HID, const float* __restrict__ W2,
    const int* __restrict__ cnt, const int* __restrict__ basep,
    float* __restrict__ MOUTP)
{
    const int e = blockIdx.x & 7;
    const int idx = blockIdx.x >> 3;
    const int mt = idx % 13;
    const int rest = idx / 13;
    const int nt = rest % 6;
    const int ks = rest / 6;
    const int c = cnt[e];
    const int r0 = mt * 64;
    if (r0 >= c) return;
    const int sbase = basep[e];
    const int n0 = nt * 64;
    const int kbase = ks * 384;
    const float* W = W2 + (size_t)e * HM * DM + (size_t)kbase * DM;
    float* outp = MOUTP + (size_t)ks * MOUTSZ;
    __shared__ short Ah[64 * LD2], Al[64 * LD2], Bh[64 * LD2], Bl[64 * LD2];
    const int tid = threadIdx.x;
    const int lane = tid & 63, w = tid >> 6;
    const int wr = w >> 1, wc = w & 1;
    const int r16 = lane & 15, g = lane >> 4;
    const int sr = tid >> 4, sc = (tid & 15) * 4;
    const int kq = (tid >> 4) * 4;
    f32x4 acc[2][2] = {};
    for (int k0 = 0; k0 < 384; k0 += 64) {
        #pragma unroll
        for (int p = 0; p < 4; ++p) {
            int r = sr + p * 16;
            int m = r0 + r;
            float4 a4 = make_float4(0.f, 0.f, 0.f, 0.f);
            if (m < c) a4 = *(const float4*)(HID + (size_t)(sbase + m) * HM + kbase + k0 + sc);
            short4 ah, al;
            f2bf2(a4.x, ah.x, al.x); f2bf2(a4.y, ah.y, al.y);
            f2bf2(a4.z, ah.z, al.z); f2bf2(a4.w, ah.w, al.w);
            *(short4*)&Ah[r * LD2 + sc] = ah; *(short4*)&Al[r * LD2 + sc] = al;
        }
        {
            float4 b4[4];
            #pragma unroll
            for (int i = 0; i < 4; ++i)
                b4[i] = *(const float4*)(W + (size_t)(k0 + kq + i) * DM + n0 + sc);
            float col[4][4] = {
                { b4[0].x, b4[1].x, b4[2].x, b4[3].x },
                { b4[0].y, b4[1].y, b4[2].y, b4[3].y },
                { b4[0].z, b4[1].z, b4[2].z, b4[3].z },
                { b4[0].w, b4[1].w, b4[2].w, b4[3].w } };
            #pragma unroll
            for (int u = 0; u < 4; ++u) {
                short4 hh, ll;
                f2bf2(col[u][0], hh.x, ll.x); f2bf2(col[u][1], hh.y, ll.y);
                f2bf2(col[u][2], hh.z, ll.z); f2bf2(col[u][3], hh.w, ll.w);
                *(short4*)&Bh[(sc + u) * LD2 + kq] = hh;
                *(short4*)&Bl[(sc + u) * LD2 + kq] = ll;
            }
        }
        __syncthreads();
        #pragma unroll
        for (int kk = 0; kk < 2; ++kk) {
            bf16x8 afh[2], afl[2], bfh[2], bfl[2];
            #pragma unroll
            for (int i = 0; i < 2; ++i) {
                int off = (wr * 32 + i * 16 + r16) * LD2 + kk * 32 + g * 8;
                afh[i] = *(const bf16x8*)&Ah[off];
                afl[i] = *(const bf16x8*)&Al[off];
            }
            #pragma unroll
            for (int j = 0; j < 2; ++j) {
                int off = (wc * 32 + j * 16 + r16) * LD2 + kk * 32 + g * 8;
                bfh[j] = *(const bf16x8*)&Bh[off];
                bfl[j] = *(const bf16x8*)&Bl[off];
            }
            #pragma unroll
            for (int i = 0; i < 2; ++i)
                #pragma unroll
                for (int j = 0; j < 2; ++j) {
                    acc[i][j] = __builtin_amdgcn_mfma_f32_16x16x32_bf16(afl[i], bfh[j], acc[i][j], 0, 0, 0);
                    acc[i][j] = __builtin_amdgcn_mfma_f32_16x16x32_bf16(afh[i], bfl[j], acc[i][j], 0, 0, 0);
                    acc[i][j] = __builtin_amdgcn_mfma_f32_16x16x32_bf16(afh[i], bfh[j], acc[i][j], 0, 0, 0);
                }
        }
        __syncthreads();
    }
    #pragma unroll
    for (int i = 0; i < 2; ++i) {
        #pragma unroll
        for (int j = 0; j < 2; ++j) {
            int n = n0 + wc * 32 + j * 16 + r16;
            #pragma unroll
            for (int r = 0; r < 4; ++r) {
                int m = r0 + wr * 32 + i * 16 + g * 4 + r;
                if (m < c)
                    outp[(size_t)(sbase + m) * DM + n] = acc[i][j][r];
            }
        }
    }
}

// ---------------- combine ----------------
__global__ void k_combine(const float* __restrict__ MOUTP, const int* __restrict__ slot_of,
                          const int* __restrict__ eidx, const float* __restrict__ egate,
                          const float* __restrict__ B2, float* __restrict__ H) {
    int t = blockIdx.x;
    int s0 = slot_of[2 * t], s1 = slot_of[2 * t + 1];
    int e0 = eidx[2 * t], e1 = eidx[2 * t + 1];
    float g0 = egate[2 * t], g1 = egate[2 * t + 1];
    for (int d = threadIdx.x; d < DM; d += 128) {
        float v0 = B2[(size_t)e0 * DM + d];
        float v1 = B2[(size_t)e1 * DM + d];
        #pragma unroll
        for (int p = 0; p < 4; ++p) {
            v0 += MOUTP[(size_t)p * MOUTSZ + (size_t)s0 * DM + d];
            v1 += MOUTP[(size_t)p * MOUTSZ + (size_t)s1 * DM + d];
        }
        H[(size_t)t * DM + d] += g0 * v0 + g1 * v1;
    }
}

extern "C" void kernel_launch(void* const* d_in, const int* in_sizes, int n_in,
                              void* d_out, int out_size, void* d_ws, size_t ws_size,
                              hipStream_t stream) {
    const float* x         = (const float*)d_in[0];
    const float* patch_w   = (const float*)d_in[1];
    const float* patch_b   = (const float*)d_in[2];
    const float* cls_token = (const float*)d_in[3];
    const float* pos_embed = (const float*)d_in[4];
    const float* ln1_w     = (const float*)d_in[5];
    const float* ln1_b     = (const float*)d_in[6];
    const float* qkv_w     = (const float*)d_in[7];
    const float* qkv_b     = (const float*)d_in[8];
    const float* proj_w    = (const float*)d_in[9];
    const float* proj_b    = (const float*)d_in[10];
    const float* ln2_w     = (const float*)d_in[11];
    const float* ln2_b     = (const float*)d_in[12];
    const float* fc1_w     = (const float*)d_in[13];
    const float* fc1_b     = (const float*)d_in[14];
    const float* fc2_w     = (const float*)d_in[15];
    const float* fc2_b     = (const float*)d_in[16];
    const float* gate_w    = (const float*)d_in[17];
    const float* moe_w1    = (const float*)d_in[18];
    const float* moe_b1    = (const float*)d_in[19];
    const float* moe_w2    = (const float*)d_in[20];
    const float* moe_b2    = (const float*)d_in[21];
    const float* lnf_w     = (const float*)d_in[22];
    const float* lnf_b     = (const float*)d_in[23];
    float* out = (float*)d_out;

    float* wsf = (float*)d_ws;
    float* regA     = wsf;
    float* patches  = regA;                 // 784*768
    float* patchout = regA + 602112;        // 784*384
    float* moehid   = regA;                 // 1576*1536 = 2420736
    float* h     = regA + 2420736;          // 788*384
    float* spare = h + 302592;              // layout stability
    float* qkvb  = spare + 302592;          // 788*1152
    float* attno = qkvb + 907776;           // 788*384
    float* regC  = attno + 302592;          // S / dense-hid (1210368 floats)
    float* S    = regC;
    float* hid  = regC;
    float* mout4 = qkvb;                    // 4*605184 spans qkvb..end(regC)
    float* egate = regC + 1210368;
    int* ib       = (int*)(egate + 1576);
    int* eidx     = ib;
    int* slot_tok = ib + 1576;
    int* slot_of  = ib + 3152;
    int* cnt      = ib + 4728;
    int* basep    = ib + 4736;
    float* lnstat = (float*)(ib + 4752);    // TT*2 floats

    // ---- patch embed ----
    k_im2col<<<784, 256, 0, stream>>>(x, patches);
    k_gemm_mfma<<<96, 256, 0, stream>>>(patches, patch_w, nullptr, patchout,
                                        784, DM, 768, 0, 13, 6, 0, 1, nullptr, nullptr);
    k_assemble<<<TT, 128, 0, stream>>>(patchout, patch_b, cls_token, pos_embed, h);

    for (int l = 0; l < 12; ++l) {
        // attention: 32-row-tile GEMM (LN fused). MT=25, NT=18 -> grid 8*25*3 = 600
        k_gemm32<<<600, 256, 0, stream>>>(h, qkv_w + (size_t)l * 1152 * DM,
                                          qkv_b + l * 1152, qkvb, TT, 1152, DM, 8,
                                          25, 18, ln1_w + l * DM, ln1_b + l * DM);
        k_scoresm<<<dim3(7, NBATCH * NHEAD), 256, 0, stream>>>(qkvb, S);
        k_pv<<<dim3(7, NBATCH * NHEAD), 256, 0, stream>>>(S, qkvb, attno);
        // proj: K-split 2, atomic accumulate into h. grid 8*2*6*2 = 192
        k_gemm_mfma<<<192, 256, 0, stream>>>(attno, proj_w + (size_t)l * DM * DM,
                                             proj_b + l * DM, h, TT, DM, DM, 16,
                                             13, 6, 0, 2, nullptr, nullptr);
        // ffn
        int j = l >> 1;
        if ((l & 1) == 0) {
            // fc1: 32-row-tile GEMM (LN fused, gelu out). MT=25, NT=24 -> grid 8*25*3 = 600
            k_gemm32<<<600, 256, 0, stream>>>(h, fc1_w + (size_t)j * HM * DM,
                                              fc1_b + j * HM, hid, TT, HM, DM, 9,
                                              25, 24, ln2_w + l * DM, ln2_b + l * DM);
            // fc2: K-split 4, atomic accumulate into h. grid 8*4*6*2 = 384
            k_gemm_mfma<<<384, 256, 0, stream>>>(hid, fc2_w + (size_t)j * DM * HM,
                                                 fc2_b + j * DM, h, TT, DM, HM, 16,
                                                 13, 6, 0, 4, nullptr, nullptr);
        } else {
            k_route_ln<<<197, 256, 0, stream>>>(h, lnstat, ln2_w + l * DM, ln2_b + l * DM,
                                                gate_w + (size_t)j * DM * NEXP, eidx, egate);
            k_pscatter<<<1, 256, 0, stream>>>(cnt, basep, eidx, slot_tok, slot_of);
            k_moe1_mfma<<<8 * 13 * 24, 256, 0, stream>>>(
                h, lnstat, ln2_w + l * DM, ln2_b + l * DM,
                moe_w1 + (size_t)j * NEXP * DM * HM, moe_b1 + (size_t)j * NEXP * HM,
                slot_tok, cnt, basep, moehid);
            k_moe2_mfma<<<8 * 13 * 24, 256, 0, stream>>>(
                moehid, moe_w2 + (size_t)j * NEXP * HM * DM, cnt, basep, mout4);
            k_combine<<<TT, 128, 0, stream>>>(mout4, slot_of, eidx, egate,
                                              moe_b2 + (size_t)j * NEXP * DM, h);
        }
    }
    k_ln<<<TT, 64, 0, stream>>>(h, lnf_w, lnf_b, out);
}